// Round 10
// baseline (493.289 us; speedup 1.0000x reference)
//
#include <hip/hip_runtime.h>
#include <hip/hip_bf16.h>
#include <math.h>

#define NN 50000
#define NE0 800000
#define ETOT (NE0 + NN)
#define NG 64
#define SCAN_BLKS ((NN + 63) / 64)   // 782
#define DMAX_THR 8.0f                // defer-max threshold (exp headroom e^8)

typedef __bf16 bf16x8 __attribute__((ext_vector_type(8)));
typedef float  f32x4  __attribute__((ext_vector_type(4)));

__device__ __forceinline__ float bf2f(unsigned short u) {
    return __uint_as_float(((unsigned)u) << 16);
}
__device__ __forceinline__ unsigned short f2bf(float f) {
    unsigned u = __float_as_uint(f);
    return (unsigned short)((u + 0x7FFFu + ((u >> 16) & 1u)) >> 16);  // RNE
}

__device__ __forceinline__ void edge_sd(const int* __restrict__ ei, int e, int& s, int& d) {
    if (e < NE0) { s = ei[e]; d = ei[NE0 + e]; }
    else { s = e - NE0; d = s; }
}

// ---------------- CSR build (by dst) ----------------
__global__ __launch_bounds__(256)
void hist_dst(const int* __restrict__ ei, int* __restrict__ deg) {
    int e = blockIdx.x * blockDim.x + threadIdx.x;
    if (e >= ETOT) return;
    int s, d; edge_sd(ei, e, s, d); (void)s;
    atomicAdd(&deg[d], 1);
}

__global__ __launch_bounds__(64)
void scan1(const int* __restrict__ deg, int* __restrict__ psum) {
    int i = blockIdx.x * 64 + threadIdx.x;
    int v = (i < NN) ? deg[i] : 0;
#pragma unroll
    for (int off = 1; off < 64; off <<= 1) {
        int t = __shfl_up(v, off);
        if ((int)threadIdx.x >= off) v += t;
    }
    if (threadIdx.x == 63) psum[blockIdx.x] = v;
}

__global__ __launch_bounds__(1024)
void scan2(int* __restrict__ psum) {
    __shared__ int sm[1024];
    int t = threadIdx.x;
    sm[t] = (t < SCAN_BLKS) ? psum[t] : 0;
    __syncthreads();
    for (int off = 1; off < 1024; off <<= 1) {
        int v = (t >= off) ? sm[t - off] : 0;
        __syncthreads();
        sm[t] += v;
        __syncthreads();
    }
    if (t < SCAN_BLKS) psum[t] = (t == 0) ? 0 : sm[t - 1];
}

__global__ __launch_bounds__(64)
void scan3(const int* __restrict__ deg, const int* __restrict__ psum,
           int* __restrict__ rowptr) {
    int i = blockIdx.x * 64 + threadIdx.x;
    int v = (i < NN) ? deg[i] : 0;
    int inc = v;
#pragma unroll
    for (int off = 1; off < 64; off <<= 1) {
        int t = __shfl_up(inc, off);
        if ((int)threadIdx.x >= off) inc += t;
    }
    int excl = inc - v + psum[blockIdx.x];
    if (i < NN) rowptr[i] = excl;
    if (i == NN - 1) rowptr[NN] = excl + v;   // == ETOT
}

__global__ __launch_bounds__(256)
void scatter_csr(const int* __restrict__ ei, int* __restrict__ cursor,
                 int* __restrict__ col) {
    int e = blockIdx.x * blockDim.x + threadIdx.x;
    if (e >= ETOT) return;
    int s, d; edge_sd(ei, e, s, d);
    int pos = atomicAdd(&cursor[d], 1);
    col[pos] = s;
}

// ---------------- weight pre-pack (all 4 matrices, one launch) ----------------
__device__ __forceinline__ void wfrag_one(const float* W, unsigned short* Wf,
                                          int r, int KB, int NOUT) {
    int j = r & 7;
    int l = (r >> 3) & 63;
    int rest = r >> 9;
    int kb = rest % KB, t = rest / KB;
    int k = kb * 32 + (l >> 4) * 8 + j;
    int colj = t * 16 + (l & 15);
    Wf[r] = f2bf(W[(size_t)k * NOUT + colj]);
}
__global__ __launch_bounds__(256)
void wfrag_all(const float* __restrict__ W2l, const float* __restrict__ W2r,
               const float* __restrict__ W3l, const float* __restrict__ W3r,
               unsigned short* __restrict__ Wf2l, unsigned short* __restrict__ Wf2r,
               unsigned short* __restrict__ Wf3l, unsigned short* __restrict__ Wf3r) {
    int tid = blockIdx.x * 256 + threadIdx.x;   // [0, 4*32768)
    int seg = tid >> 15;
    int r = tid & 32767;
    if (seg == 0)      wfrag_one(W2l, Wf2l, r, 8, 128);
    else if (seg == 1) wfrag_one(W2r, Wf2r, r, 8, 128);
    else if (seg == 2) wfrag_one(W3l, Wf3l, r, 4, 256);
    else               wfrag_one(W3r, Wf3r, r, 4, 256);
}

// ---------------- BLR table: BLR[n,ch] = b1l[ch] + b1r[ch] + sum_k x[n,k] W1r[k,ch] ----------------
__global__ __launch_bounds__(256)
void blr_prep(const float* __restrict__ X, const float* __restrict__ W1r,
              const float* __restrict__ b1r, const float* __restrict__ b1l,
              float* __restrict__ out) {
    int j = blockIdx.x * 64 + (threadIdx.x & 63);
    int row0 = (blockIdx.y * 4 + (threadIdx.x >> 6)) * 8;
    float w0 = W1r[j], w1 = W1r[256 + j], w2 = W1r[512 + j], w3 = W1r[768 + j];
    float bj = b1r[j] + b1l[j];
#pragma unroll
    for (int r = 0; r < 8; ++r) {
        int row = row0 + r;
        if (row >= NN) break;
        float4 xv = *reinterpret_cast<const float4*>(X + (size_t)row * 4);
        out[(size_t)row * 256 + j] =
            fmaf(xv.x, w0, fmaf(xv.y, w1, fmaf(xv.z, w2, fmaf(xv.w, w3, bj))));
    }
}

// ---------------- Layer 1 fully fused (wave/node, 4-edge batch, double-buffered prefetch) ----------------
__global__ __launch_bounds__(256)
void gat1_fused(const float* __restrict__ x,
                const int* __restrict__ rowptr, const int* __restrict__ col,
                const float* __restrict__ BLR,
                const float* __restrict__ W1l, const float* __restrict__ b1l,
                const float* __restrict__ a1, const float* __restrict__ c1b,
                unsigned short* __restrict__ out) {
    int lane = threadIdx.x & 63;
    int node = (blockIdx.x * blockDim.x + threadIdx.x) >> 6;
    if (node >= NN) return;
    int ch0 = lane * 4;

    float wl[4][4];
#pragma unroll
    for (int k = 0; k < 4; ++k) {
        float4 l4 = *reinterpret_cast<const float4*>(W1l + k * 256 + ch0);
        wl[k][0] = l4.x; wl[k][1] = l4.y; wl[k][2] = l4.z; wl[k][3] = l4.w;
    }
    float4 av  = *reinterpret_cast<const float4*>(a1 + ch0);
    float ar[4] = { av.x, av.y, av.z, av.w };
    float4 blv = *reinterpret_cast<const float4*>(b1l + ch0);
    float4 cbv = *reinterpret_cast<const float4*>(c1b + ch0);
    float obias[4] = { blv.x + cbv.x, blv.y + cbv.y, blv.z + cbv.z, blv.w + cbv.w };

    const float4* x4 = reinterpret_cast<const float4*>(x);

    float4 blrv = *reinterpret_cast<const float4*>(BLR + (size_t)node * 256 + ch0);
    float blr[4] = { blrv.x, blrv.y, blrv.z, blrv.w };

    float m = -INFINITY, l = 0.f;
    float ax = 0.f, ay = 0.f, az = 0.f, aw = 0.f;

    int beg = rowptr[node], end = rowptr[node + 1];

    auto GATHER = [&](float4 (&v)[4], int base) {
#pragma unroll
        for (int q = 0; q < 4; ++q) v[q] = x4[col[base + q]];
    };
    auto COMPUTE = [&](const float4 (&v)[4]) {
        float dd[4];
#pragma unroll
        for (int q = 0; q < 4; ++q) {
            float d = 0.f;
#pragma unroll
            for (int p = 0; p < 4; ++p) {
                float u = fmaf(v[q].x, wl[0][p], fmaf(v[q].y, wl[1][p],
                          fmaf(v[q].z, wl[2][p], fmaf(v[q].w, wl[3][p], blr[p]))));
                u = u > 0.f ? u : 0.2f * u;
                d = fmaf(u, ar[p], d);
            }
            dd[q] = d;
        }
#pragma unroll
        for (int off = 8; off >= 1; off >>= 1) {
#pragma unroll
            for (int q = 0; q < 4; ++q) dd[q] += __shfl_xor(dd[q], off);
        }
        float pmax = fmaxf(fmaxf(dd[0], dd[1]), fmaxf(dd[2], dd[3]));
        if (pmax > m + DMAX_THR) {           // rare path
            float sc = __expf(m - pmax);
            l *= sc; ax *= sc; ay *= sc; az *= sc; aw *= sc;
            m = pmax;
        }
        float p0 = __expf(dd[0] - m), p1 = __expf(dd[1] - m);
        float p2 = __expf(dd[2] - m), p3 = __expf(dd[3] - m);
        l += (p0 + p1) + (p2 + p3);
        ax += fmaf(p0, v[0].x, p1 * v[1].x) + fmaf(p2, v[2].x, p3 * v[3].x);
        ay += fmaf(p0, v[0].y, p1 * v[1].y) + fmaf(p2, v[2].y, p3 * v[3].y);
        az += fmaf(p0, v[0].z, p1 * v[1].z) + fmaf(p2, v[2].z, p3 * v[3].z);
        aw += fmaf(p0, v[0].w, p1 * v[1].w) + fmaf(p2, v[2].w, p3 * v[3].w);
    };

    int n4 = (end - beg) & ~3;
    {
        float4 vA[4], vB[4];
        int i = 0;
        if (n4) {
            GATHER(vA, beg);
            for (i = 0; i + 8 <= n4; i += 8) {
                GATHER(vB, beg + i + 4);
                COMPUTE(vA);
                if (i + 12 <= n4) GATHER(vA, beg + i + 8);
                COMPUTE(vB);
            }
            if (i + 4 <= n4) COMPUTE(vA);
        }
    }
    for (int idx = beg + n4; idx < end; ++idx) {
        float4 v0 = x4[col[idx]];
        float d0 = 0.f;
#pragma unroll
        for (int p = 0; p < 4; ++p) {
            float u0 = fmaf(v0.x, wl[0][p], fmaf(v0.y, wl[1][p],
                       fmaf(v0.z, wl[2][p], fmaf(v0.w, wl[3][p], blr[p]))));
            u0 = u0 > 0.f ? u0 : 0.2f * u0;
            d0 = fmaf(u0, ar[p], d0);
        }
#pragma unroll
        for (int off = 8; off >= 1; off >>= 1) d0 += __shfl_xor(d0, off);
        if (d0 > m + DMAX_THR) {
            float sc = __expf(m - d0);
            l *= sc; ax *= sc; ay *= sc; az *= sc; aw *= sc;
            m = d0;
        }
        float p0 = __expf(d0 - m);
        l += p0;
        ax = fmaf(p0, v0.x, ax);
        ay = fmaf(p0, v0.y, ay);
        az = fmaf(p0, v0.z, az);
        aw = fmaf(p0, v0.w, aw);
    }
    float inv = 1.f / (l + 1e-16f);
    unsigned short o[4];
#pragma unroll
    for (int p = 0; p < 4; ++p) {
        float v = fmaf(ax, wl[0][p], fmaf(ay, wl[1][p],
                  fmaf(az, wl[2][p], aw * wl[3][p]))) * inv + obias[p];
        o[p] = f2bf(fmaxf(v, 0.f));
    }
    *reinterpret_cast<ushort4*>(out + (size_t)node * 256 + ch0) =
        make_ushort4(o[0], o[1], o[2], o[3]);
}

// ---------------- fused MFMA GEMM ----------------
template<int KIN, int NOUT>
__global__ __launch_bounds__(256)
void gemm_mfma2(const unsigned short* __restrict__ X,
                const unsigned short* __restrict__ WfL, const float* __restrict__ bL,
                unsigned short* __restrict__ outL,
                const unsigned short* __restrict__ WfR, const float* __restrict__ bR,
                unsigned short* __restrict__ outR) {
    constexpr int KB = KIN / 32, NT = NOUT / 16;
    int lane = threadIdx.x & 63;
    int wv = threadIdx.x >> 6;
    int row0 = blockIdx.x * 64 + wv * 16;
    int r16 = lane & 15, kg = lane >> 4;

    int arow = row0 + r16; if (arow >= NN) arow = NN - 1;
    const unsigned short* xrow = X + (size_t)arow * KIN + kg * 8;
    bf16x8 af[KB];
#pragma unroll
    for (int kb = 0; kb < KB; ++kb)
        af[kb] = *reinterpret_cast<const bf16x8*>(xrow + kb * 32);

    const unsigned short* Wf[2] = { WfL, WfR };
    const float* bb[2] = { bL, bR };
    unsigned short* oo[2] = { outL, outR };

#pragma unroll
    for (int w = 0; w < 2; ++w) {
        const bf16x8* wbase = reinterpret_cast<const bf16x8*>(Wf[w]) + lane;
        const float* bw = bb[w];
        unsigned short* ow = oo[w];
#pragma unroll 1
        for (int t = 0; t < NT; ++t) {
            f32x4 acc = {0.f, 0.f, 0.f, 0.f};
            const bf16x8* wp = wbase + (size_t)t * KB * 64;
#pragma unroll
            for (int kb = 0; kb < KB; ++kb)
                acc = __builtin_amdgcn_mfma_f32_16x16x32_bf16(af[kb], wp[kb * 64], acc, 0, 0, 0);
            float bv = bw[t * 16 + r16];
#pragma unroll
            for (int rg = 0; rg < 4; ++rg) {
                int row = row0 + kg * 4 + rg;
                if (row < NN)
                    ow[(size_t)row * NOUT + t * 16 + r16] = f2bf(acc[rg] + bv);
            }
        }
    }
}

// ---------------- GATv2 aggregation (layers 2/3): wave/node, 4-edge batch, double-buffered ----------------
template<int H, int C, bool RELU, bool OUT_BF16>
__global__ __launch_bounds__(256)
void gat_fused(const unsigned short* __restrict__ xl, const unsigned short* __restrict__ xr,
               const int* __restrict__ rowptr, const int* __restrict__ col,
               const float* __restrict__ att, const float* __restrict__ bias,
               void* __restrict__ outv) {
    constexpr int HC = H * C;
    constexpr int CPL = HC / 64;     // 2 (L2), 4 (L3)
    constexpr int GRP = C / CPL;     // 32, 64
    int lane = threadIdx.x & 63;
    int node = (blockIdx.x * blockDim.x + threadIdx.x) >> 6;
    if (node >= NN) return;
    int ch0 = lane * CPL;

    float areg[CPL], breg[CPL];
#pragma unroll
    for (int p = 0; p < CPL; ++p) { areg[p] = att[ch0 + p]; breg[p] = bias[ch0 + p]; }

    float xrv[CPL];
    if constexpr (CPL == 4) {
        ushort4 u = *reinterpret_cast<const ushort4*>(xr + (size_t)node * HC + ch0);
        xrv[0] = bf2f(u.x); xrv[1] = bf2f(u.y); xrv[2] = bf2f(u.z); xrv[3] = bf2f(u.w);
    } else {
        ushort2 u = *reinterpret_cast<const ushort2*>(xr + (size_t)node * HC + ch0);
        xrv[0] = bf2f(u.x); xrv[1] = bf2f(u.y);
    }
    float m = -INFINITY, l = 0.f, acc[CPL];
#pragma unroll
    for (int p = 0; p < CPL; ++p) acc[p] = 0.f;

    int beg = rowptr[node], end = rowptr[node + 1];

    auto GATHER = [&](float (&a)[4][CPL], int base) {
#pragma unroll
        for (int q = 0; q < 4; ++q) {
            int s = col[base + q];
            if constexpr (CPL == 4) {
                ushort4 u = *reinterpret_cast<const ushort4*>(xl + (size_t)s * HC + ch0);
                a[q][0] = bf2f(u.x); a[q][1] = bf2f(u.y); a[q][2] = bf2f(u.z); a[q][3] = bf2f(u.w);
            } else {
                ushort2 u = *reinterpret_cast<const ushort2*>(xl + (size_t)s * HC + ch0);
                a[q][0] = bf2f(u.x); a[q][1] = bf2f(u.y);
            }
        }
    };
    auto COMPUTE = [&](const float (&a)[4][CPL]) {
        float dd[4];
#pragma unroll
        for (int q = 0; q < 4; ++q) {
            float d = 0.f;
#pragma unroll
            for (int p = 0; p < CPL; ++p) {
                float v = a[q][p] + xrv[p];
                v = v > 0.f ? v : 0.2f * v;
                d = fmaf(v, areg[p], d);
            }
            dd[q] = d;
        }
#pragma unroll
        for (int off = GRP >> 1; off >= 1; off >>= 1) {
#pragma unroll
            for (int q = 0; q < 4; ++q) dd[q] += __shfl_xor(dd[q], off);
        }
        float pmax = fmaxf(fmaxf(dd[0], dd[1]), fmaxf(dd[2], dd[3]));
        if (pmax > m + DMAX_THR) {
            float sc = __expf(m - pmax);
            l *= sc;
#pragma unroll
            for (int p = 0; p < CPL; ++p) acc[p] *= sc;
            m = pmax;
        }
        float p0 = __expf(dd[0] - m), p1 = __expf(dd[1] - m);
        float p2 = __expf(dd[2] - m), p3 = __expf(dd[3] - m);
        l += (p0 + p1) + (p2 + p3);
#pragma unroll
        for (int p = 0; p < CPL; ++p)
            acc[p] += fmaf(p0, a[0][p], p1 * a[1][p]) + fmaf(p2, a[2][p], p3 * a[3][p]);
    };

    int n4 = (end - beg) & ~3;
    {
        float aA[4][CPL], aB[4][CPL];
        int i = 0;
        if (n4) {
            GATHER(aA, beg);
            for (i = 0; i + 8 <= n4; i += 8) {
                GATHER(aB, beg + i + 4);
                COMPUTE(aA);
                if (i + 12 <= n4) GATHER(aA, beg + i + 8);
                COMPUTE(aB);
            }
            if (i + 4 <= n4) COMPUTE(aA);
        }
    }
    for (int idx = beg + n4; idx < end; ++idx) {
        int s0 = col[idx];
        float a0[CPL];
        if constexpr (CPL == 4) {
            ushort4 u0 = *reinterpret_cast<const ushort4*>(xl + (size_t)s0 * HC + ch0);
            a0[0] = bf2f(u0.x); a0[1] = bf2f(u0.y); a0[2] = bf2f(u0.z); a0[3] = bf2f(u0.w);
        } else {
            ushort2 u0 = *reinterpret_cast<const ushort2*>(xl + (size_t)s0 * HC + ch0);
            a0[0] = bf2f(u0.x); a0[1] = bf2f(u0.y);
        }
        float d0 = 0.f;
#pragma unroll
        for (int p = 0; p < CPL; ++p) {
            float v0 = a0[p] + xrv[p];
            v0 = v0 > 0.f ? v0 : 0.2f * v0;
            d0 = fmaf(v0, areg[p], d0);
        }
#pragma unroll
        for (int off = GRP >> 1; off >= 1; off >>= 1) d0 += __shfl_xor(d0, off);
        if (d0 > m + DMAX_THR) {
            float sc = __expf(m - d0);
            l *= sc;
#pragma unroll
            for (int p = 0; p < CPL; ++p) acc[p] *= sc;
            m = d0;
        }
        float p0 = __expf(d0 - m);
        l += p0;
#pragma unroll
        for (int p = 0; p < CPL; ++p)
            acc[p] = fmaf(p0, a0[p], acc[p]);
    }
    float inv = 1.f / (l + 1e-16f);
    float o[CPL];
#pragma unroll
    for (int p = 0; p < CPL; ++p) {
        float v = acc[p] * inv + breg[p];
        if (RELU) v = fmaxf(v, 0.f);
        o[p] = v;
    }
    if constexpr (OUT_BF16) {
        unsigned short* out = (unsigned short*)outv;
        if constexpr (CPL == 4) {
            *reinterpret_cast<ushort4*>(out + (size_t)node * HC + ch0) =
                make_ushort4(f2bf(o[0]), f2bf(o[1]), f2bf(o[2]), f2bf(o[3]));
        } else {
            *reinterpret_cast<ushort2*>(out + (size_t)node * HC + ch0) =
                make_ushort2(f2bf(o[0]), f2bf(o[1]));
        }
    } else {
        float* out = (float*)outv;
        if constexpr (CPL == 4) {
            *reinterpret_cast<float4*>(out + (size_t)node * HC + ch0) =
                make_float4(o[0], o[1], o[2], o[3]);
        } else {
            *reinterpret_cast<float2*>(out + (size_t)node * HC + ch0) =
                make_float2(o[0], o[1]);
        }
    }
}

// ---------------- pool + head MLP ----------------
__global__ __launch_bounds__(64)
void graph_bounds(const int* __restrict__ batch, float* __restrict__ cnt) {
    int g = threadIdx.x;
    if (g >= NG) return;
    int lo = 0, hi = NN;
    while (lo < hi) { int mid = (lo + hi) >> 1; if (batch[mid] < g) lo = mid + 1; else hi = mid; }
    int lo2 = lo, hi2 = NN;
    while (lo2 < hi2) { int mid = (lo2 + hi2) >> 1; if (batch[mid] < g + 1) lo2 = mid + 1; else hi2 = mid; }
    cnt[g] = (float)(lo2 - lo);
}

__global__ __launch_bounds__(256)
void pool_sum(const float* __restrict__ h, const int* __restrict__ batch,
              float* pooled) {
    __shared__ int gb[32];
    int c = threadIdx.x;
    int n0 = blockIdx.x * 32;
    int n1 = min(n0 + 32, NN);
    int cnt = n1 - n0;
    if (c < cnt) gb[c] = batch[n0 + c];
    __syncthreads();
    if (gb[0] == gb[cnt - 1]) {
        float acc = 0.f;
#pragma unroll 4
        for (int i = 0; i < cnt; ++i) acc += h[(size_t)(n0 + i) * 256 + c];
        atomicAdd(&pooled[gb[0] * 256 + c], acc);
    } else {
        int cur = gb[0]; float acc = 0.f;
        for (int i = 0; i < cnt; ++i) {
            int g = gb[i];
            if (g != cur) { atomicAdd(&pooled[cur * 256 + c], acc); acc = 0.f; cur = g; }
            acc += h[(size_t)(n0 + i) * 256 + c];
        }
        atomicAdd(&pooled[cur * 256 + c], acc);
    }
}

__global__ __launch_bounds__(256)
void mlp_ln(const float* __restrict__ pooled, const float* __restrict__ cnt,
            const float* __restrict__ We1, const float* __restrict__ be1,
            const float* __restrict__ We2, const float* __restrict__ be2,
            const float* __restrict__ lng, const float* __restrict__ lnb,
            float* __restrict__ out) {
    __shared__ float p[256];
    __shared__ float t[512];
    __shared__ float red[8];
    int g = blockIdx.x, tid = threadIdx.x;
    p[tid] = pooled[g * 256 + tid] / fmaxf(cnt[g], 1.0f);
    __syncthreads();
    for (int jj = tid; jj < 512; jj += 256) {
        float s = be1[jj];
        for (int k = 0; k < 256; ++k) s = fmaf(p[k], We1[(size_t)k * 512 + jj], s);
        t[jj] = fmaxf(s, 0.f);
    }
    __syncthreads();
    float z = be2[tid];
    for (int k = 0; k < 512; ++k) z = fmaf(t[k], We2[(size_t)k * 256 + tid], z);
    float sv = z, sq = z * z;
#pragma unroll
    for (int off = 32; off >= 1; off >>= 1) {
        sv += __shfl_xor(sv, off);
        sq += __shfl_xor(sq, off);
    }
    int wv = tid >> 6;
    if ((tid & 63) == 0) { red[wv] = sv; red[4 + wv] = sq; }
    __syncthreads();
    float tot = red[0] + red[1] + red[2] + red[3];
    float totq = red[4] + red[5] + red[6] + red[7];
    float mu = tot * (1.f / 256.f);
    float var = totq * (1.f / 256.f) - mu * mu;
    float r = rsqrtf(var + 1e-5f);
    out[g * 256 + tid] = (z - mu) * r * lng[tid] + lnb[tid];
}

extern "C" void kernel_launch(void* const* d_in, const int* in_sizes, int n_in,
                              void* d_out, int out_size, void* d_ws, size_t ws_size,
                              hipStream_t stream) {
    const float* x   = (const float*)d_in[0];
    const int*   ei  = (const int*)d_in[1];
    const int*   bat = (const int*)d_in[2];
    const float *W1l = (const float*)d_in[3], *b1l = (const float*)d_in[4];
    const float *W1r = (const float*)d_in[5], *b1r = (const float*)d_in[6];
    const float *a1  = (const float*)d_in[7], *c1b = (const float*)d_in[8];
    const float *W2l = (const float*)d_in[9],  *b2l = (const float*)d_in[10];
    const float *W2r = (const float*)d_in[11], *b2r = (const float*)d_in[12];
    const float *a2  = (const float*)d_in[13], *c2b = (const float*)d_in[14];
    const float *W3l = (const float*)d_in[15], *b3l = (const float*)d_in[16];
    const float *W3r = (const float*)d_in[17], *b3r = (const float*)d_in[18];
    const float *a3  = (const float*)d_in[19], *c3b = (const float*)d_in[20];
    const float *We1 = (const float*)d_in[21], *be1 = (const float*)d_in[22];
    const float *We2 = (const float*)d_in[23], *be2 = (const float*)d_in[24];
    const float *lng = (const float*)d_in[25], *lnb = (const float*)d_in[26];

    char* base = (char*)d_ws;
    size_t off = 0;
    auto nxt = [&](size_t bytes) { char* p = base + off; off = (off + bytes + 255) & ~(size_t)255; return p; };
    unsigned short* Abuf = (unsigned short*)nxt((size_t)NN * 256 * 2);
    unsigned short* Bbuf = (unsigned short*)nxt((size_t)NN * 256 * 2);
    unsigned short* Hb16 = (unsigned short*)nxt((size_t)NN * 256 * 2);
    float* Hb32 = (float*)nxt((size_t)NN * 256 * 4);
    float* BLR  = (float*)nxt((size_t)NN * 256 * 4);
    int* deg    = (int*)nxt(NN * 4);
    int* rowptr = (int*)nxt((NN + 1) * 4);
    int* cursor = (int*)nxt(NN * 4);
    int* colv   = (int*)nxt((size_t)ETOT * 4);
    int* psum   = (int*)nxt(1024 * 4);
    float* POOL = (float*)nxt(NG * 256 * 4);
    float* CNT  = (float*)nxt(NG * 4);
    unsigned short* Wf2l = (unsigned short*)nxt(256 * 128 * 2);
    unsigned short* Wf2r = (unsigned short*)nxt(256 * 128 * 2);
    unsigned short* Wf3l = (unsigned short*)nxt(128 * 256 * 2);
    unsigned short* Wf3r = (unsigned short*)nxt(128 * 256 * 2);

    const int GEMM_BLKS = (NN + 63) / 64;
    const int NB_NODE = (NN + 3) / 4;   // wave-per-node, 4 waves/block

    // ---- CSR build ----
    hipMemsetAsync(deg, 0, NN * sizeof(int), stream);
    hist_dst<<<(ETOT + 255) / 256, 256, 0, stream>>>(ei, deg);
    scan1<<<SCAN_BLKS, 64, 0, stream>>>(deg, psum);
    scan2<<<1, 1024, 0, stream>>>(psum);
    scan3<<<SCAN_BLKS, 64, 0, stream>>>(deg, psum, rowptr);
    hipMemcpyAsync(cursor, rowptr, NN * sizeof(int), hipMemcpyDeviceToDevice, stream);
    scatter_csr<<<(ETOT + 255) / 256, 256, 0, stream>>>(ei, cursor, colv);

    // ---- weight pre-pack + BLR table ----
    wfrag_all<<<(4 * 32768) / 256, 256, 0, stream>>>(W2l, W2r, W3l, W3r, Wf2l, Wf2r, Wf3l, Wf3r);
    {
        dim3 g(4, (NN + 31) / 32);
        blr_prep<<<g, 256, 0, stream>>>(x, W1r, b1r, b1l, BLR);
    }

    // ---- Layer 1: fully fused from raw x ----
    gat1_fused<<<NB_NODE, 256, 0, stream>>>(x, rowptr, colv, BLR, W1l, b1l, a1, c1b, Hb16);

    // ---- Layer 2: 256 -> (H=2,C=64) ----
    gemm_mfma2<256, 128><<<GEMM_BLKS, 256, 0, stream>>>(Hb16, Wf2l, b2l, Abuf, Wf2r, b2r, Bbuf);
    gat_fused<2, 64, true, true><<<NB_NODE, 256, 0, stream>>>(Abuf, Bbuf, rowptr, colv, a2, c2b, Hb16);

    // ---- Layer 3: 128 -> (H=1,C=256), concat=False ----
    gemm_mfma2<128, 256><<<GEMM_BLKS, 256, 0, stream>>>(Hb16, Wf3l, b3l, Abuf, Wf3r, b3r, Bbuf);
    gat_fused<1, 256, false, false><<<NB_NODE, 256, 0, stream>>>(Abuf, Bbuf, rowptr, colv, a3, c3b, Hb32);

    // ---- pool + MLP + LN ----
    hipMemsetAsync(POOL, 0, (size_t)NG * 256 * 4, stream);
    graph_bounds<<<1, 64, 0, stream>>>(bat, CNT);
    pool_sum<<<(NN + 31) / 32, 256, 0, stream>>>(Hb32, bat, POOL);
    mlp_ln<<<NG, 256, 0, stream>>>(POOL, CNT, We1, be1, We2, be2, lng, lnb, (float*)d_out);
}

// Round 11
// 472.666 us; speedup vs baseline: 1.0436x; 1.0436x over previous
//
#include <hip/hip_runtime.h>
#include <hip/hip_bf16.h>
#include <math.h>

#define NN 50000
#define NE0 800000
#define ETOT (NE0 + NN)
#define NG 64
#define SCAN_BLKS ((NN + 63) / 64)   // 782
#define DMAX_THR 8.0f                // defer-max threshold (exp headroom e^8)

typedef __bf16 bf16x8 __attribute__((ext_vector_type(8)));
typedef float  f32x4  __attribute__((ext_vector_type(4)));
typedef unsigned short us8 __attribute__((ext_vector_type(8)));

__device__ __forceinline__ float bf2f(unsigned short u) {
    return __uint_as_float(((unsigned)u) << 16);
}
__device__ __forceinline__ unsigned short f2bf(float f) {
    unsigned u = __float_as_uint(f);
    return (unsigned short)((u + 0x7FFFu + ((u >> 16) & 1u)) >> 16);  // RNE
}

__device__ __forceinline__ void edge_sd(const int* __restrict__ ei, int e, int& s, int& d) {
    if (e < NE0) { s = ei[e]; d = ei[NE0 + e]; }
    else { s = e - NE0; d = s; }
}

// ---------------- CSR build (by dst) ----------------
__global__ __launch_bounds__(256)
void hist_dst(const int* __restrict__ ei, int* __restrict__ deg) {
    int e = blockIdx.x * blockDim.x + threadIdx.x;
    if (e >= ETOT) return;
    int s, d; edge_sd(ei, e, s, d); (void)s;
    atomicAdd(&deg[d], 1);
}

__global__ __launch_bounds__(64)
void scan1(const int* __restrict__ deg, int* __restrict__ psum) {
    int i = blockIdx.x * 64 + threadIdx.x;
    int v = (i < NN) ? deg[i] : 0;
#pragma unroll
    for (int off = 1; off < 64; off <<= 1) {
        int t = __shfl_up(v, off);
        if ((int)threadIdx.x >= off) v += t;
    }
    if (threadIdx.x == 63) psum[blockIdx.x] = v;
}

__global__ __launch_bounds__(1024)
void scan2(int* __restrict__ psum) {
    __shared__ int sm[1024];
    int t = threadIdx.x;
    sm[t] = (t < SCAN_BLKS) ? psum[t] : 0;
    __syncthreads();
    for (int off = 1; off < 1024; off <<= 1) {
        int v = (t >= off) ? sm[t - off] : 0;
        __syncthreads();
        sm[t] += v;
        __syncthreads();
    }
    if (t < SCAN_BLKS) psum[t] = (t == 0) ? 0 : sm[t - 1];
}

__global__ __launch_bounds__(64)
void scan3(const int* __restrict__ deg, const int* __restrict__ psum,
           int* __restrict__ rowptr) {
    int i = blockIdx.x * 64 + threadIdx.x;
    int v = (i < NN) ? deg[i] : 0;
    int inc = v;
#pragma unroll
    for (int off = 1; off < 64; off <<= 1) {
        int t = __shfl_up(inc, off);
        if ((int)threadIdx.x >= off) inc += t;
    }
    int excl = inc - v + psum[blockIdx.x];
    if (i < NN) rowptr[i] = excl;
    if (i == NN - 1) rowptr[NN] = excl + v;   // == ETOT
}

__global__ __launch_bounds__(256)
void scatter_csr(const int* __restrict__ ei, int* __restrict__ cursor,
                 int* __restrict__ col) {
    int e = blockIdx.x * blockDim.x + threadIdx.x;
    if (e >= ETOT) return;
    int s, d; edge_sd(ei, e, s, d);
    int pos = atomicAdd(&cursor[d], 1);
    col[pos] = s;
}

// ---------------- weight pre-pack (all 4 matrices, one launch) ----------------
__device__ __forceinline__ void wfrag_one(const float* W, unsigned short* Wf,
                                          int r, int KB, int NOUT) {
    int j = r & 7;
    int l = (r >> 3) & 63;
    int rest = r >> 9;
    int kb = rest % KB, t = rest / KB;
    int k = kb * 32 + (l >> 4) * 8 + j;
    int colj = t * 16 + (l & 15);
    Wf[r] = f2bf(W[(size_t)k * NOUT + colj]);
}
__global__ __launch_bounds__(256)
void wfrag_all(const float* __restrict__ W2l, const float* __restrict__ W2r,
               const float* __restrict__ W3l, const float* __restrict__ W3r,
               unsigned short* __restrict__ Wf2l, unsigned short* __restrict__ Wf2r,
               unsigned short* __restrict__ Wf3l, unsigned short* __restrict__ Wf3r) {
    int tid = blockIdx.x * 256 + threadIdx.x;   // [0, 4*32768)
    int seg = tid >> 15;
    int r = tid & 32767;
    if (seg == 0)      wfrag_one(W2l, Wf2l, r, 8, 128);
    else if (seg == 1) wfrag_one(W2r, Wf2r, r, 8, 128);
    else if (seg == 2) wfrag_one(W3l, Wf3l, r, 4, 256);
    else               wfrag_one(W3r, Wf3r, r, 4, 256);
}

// ---------------- BLR table: BLR[n,ch] = b1l[ch] + b1r[ch] + sum_k x[n,k] W1r[k,ch] ----------------
__global__ __launch_bounds__(256)
void blr_prep(const float* __restrict__ X, const float* __restrict__ W1r,
              const float* __restrict__ b1r, const float* __restrict__ b1l,
              float* __restrict__ out) {
    int j = blockIdx.x * 64 + (threadIdx.x & 63);
    int row0 = (blockIdx.y * 4 + (threadIdx.x >> 6)) * 8;
    float w0 = W1r[j], w1 = W1r[256 + j], w2 = W1r[512 + j], w3 = W1r[768 + j];
    float bj = b1r[j] + b1l[j];
#pragma unroll
    for (int r = 0; r < 8; ++r) {
        int row = row0 + r;
        if (row >= NN) break;
        float4 xv = *reinterpret_cast<const float4*>(X + (size_t)row * 4);
        out[(size_t)row * 256 + j] =
            fmaf(xv.x, w0, fmaf(xv.y, w1, fmaf(xv.z, w2, fmaf(xv.w, w3, bj))));
    }
}

// ---------------- Layer 1 fully fused (wave/node, 4-edge batch, branchy defer-max) ----------------
__global__ __launch_bounds__(256)
void gat1_fused(const float* __restrict__ x,
                const int* __restrict__ rowptr, const int* __restrict__ col,
                const float* __restrict__ BLR,
                const float* __restrict__ W1l, const float* __restrict__ b1l,
                const float* __restrict__ a1, const float* __restrict__ c1b,
                unsigned short* __restrict__ out) {
    int lane = threadIdx.x & 63;
    int node = (blockIdx.x * blockDim.x + threadIdx.x) >> 6;
    if (node >= NN) return;
    int ch0 = lane * 4;

    float wl[4][4];
#pragma unroll
    for (int k = 0; k < 4; ++k) {
        float4 l4 = *reinterpret_cast<const float4*>(W1l + k * 256 + ch0);
        wl[k][0] = l4.x; wl[k][1] = l4.y; wl[k][2] = l4.z; wl[k][3] = l4.w;
    }
    float4 av  = *reinterpret_cast<const float4*>(a1 + ch0);
    float ar[4] = { av.x, av.y, av.z, av.w };
    float4 blv = *reinterpret_cast<const float4*>(b1l + ch0);
    float4 cbv = *reinterpret_cast<const float4*>(c1b + ch0);
    float obias[4] = { blv.x + cbv.x, blv.y + cbv.y, blv.z + cbv.z, blv.w + cbv.w };

    const float4* x4 = reinterpret_cast<const float4*>(x);

    float4 blrv = *reinterpret_cast<const float4*>(BLR + (size_t)node * 256 + ch0);
    float blr[4] = { blrv.x, blrv.y, blrv.z, blrv.w };

    float m = -INFINITY, l = 0.f;
    float ax = 0.f, ay = 0.f, az = 0.f, aw = 0.f;

    int beg = rowptr[node], end = rowptr[node + 1];
    int idx = beg;
    for (; idx + 3 < end; idx += 4) {
        float4 v[4];
        float dd[4];
#pragma unroll
        for (int q = 0; q < 4; ++q) v[q] = x4[col[idx + q]];
#pragma unroll
        for (int q = 0; q < 4; ++q) {
            float d = 0.f;
#pragma unroll
            for (int p = 0; p < 4; ++p) {
                float u = fmaf(v[q].x, wl[0][p], fmaf(v[q].y, wl[1][p],
                          fmaf(v[q].z, wl[2][p], fmaf(v[q].w, wl[3][p], blr[p]))));
                u = u > 0.f ? u : 0.2f * u;
                d = fmaf(u, ar[p], d);
            }
            dd[q] = d;
        }
#pragma unroll
        for (int off = 8; off >= 1; off >>= 1) {
#pragma unroll
            for (int q = 0; q < 4; ++q) dd[q] += __shfl_xor(dd[q], off);
        }
        float pmax = fmaxf(fmaxf(dd[0], dd[1]), fmaxf(dd[2], dd[3]));
        if (pmax > m + DMAX_THR) {           // rare path
            float sc = __expf(m - pmax);
            l *= sc; ax *= sc; ay *= sc; az *= sc; aw *= sc;
            m = pmax;
        }
        float p0 = __expf(dd[0] - m), p1 = __expf(dd[1] - m);
        float p2 = __expf(dd[2] - m), p3 = __expf(dd[3] - m);
        l += (p0 + p1) + (p2 + p3);
        ax += fmaf(p0, v[0].x, p1 * v[1].x) + fmaf(p2, v[2].x, p3 * v[3].x);
        ay += fmaf(p0, v[0].y, p1 * v[1].y) + fmaf(p2, v[2].y, p3 * v[3].y);
        az += fmaf(p0, v[0].z, p1 * v[1].z) + fmaf(p2, v[2].z, p3 * v[3].z);
        aw += fmaf(p0, v[0].w, p1 * v[1].w) + fmaf(p2, v[2].w, p3 * v[3].w);
    }
    for (; idx < end; ++idx) {
        float4 v0 = x4[col[idx]];
        float d0 = 0.f;
#pragma unroll
        for (int p = 0; p < 4; ++p) {
            float u0 = fmaf(v0.x, wl[0][p], fmaf(v0.y, wl[1][p],
                       fmaf(v0.z, wl[2][p], fmaf(v0.w, wl[3][p], blr[p]))));
            u0 = u0 > 0.f ? u0 : 0.2f * u0;
            d0 = fmaf(u0, ar[p], d0);
        }
#pragma unroll
        for (int off = 8; off >= 1; off >>= 1) d0 += __shfl_xor(d0, off);
        if (d0 > m + DMAX_THR) {
            float sc = __expf(m - d0);
            l *= sc; ax *= sc; ay *= sc; az *= sc; aw *= sc;
            m = d0;
        }
        float p0 = __expf(d0 - m);
        l += p0;
        ax = fmaf(p0, v0.x, ax);
        ay = fmaf(p0, v0.y, ay);
        az = fmaf(p0, v0.z, az);
        aw = fmaf(p0, v0.w, aw);
    }
    float inv = 1.f / (l + 1e-16f);
    unsigned short o[4];
#pragma unroll
    for (int p = 0; p < 4; ++p) {
        float v = fmaf(ax, wl[0][p], fmaf(ay, wl[1][p],
                  fmaf(az, wl[2][p], aw * wl[3][p]))) * inv + obias[p];
        o[p] = f2bf(fmaxf(v, 0.f));
    }
    *reinterpret_cast<ushort4*>(out + (size_t)node * 256 + ch0) =
        make_ushort4(o[0], o[1], o[2], o[3]);
}

// ---------------- fused MFMA GEMM ----------------
template<int KIN, int NOUT>
__global__ __launch_bounds__(256)
void gemm_mfma2(const unsigned short* __restrict__ X,
                const unsigned short* __restrict__ WfL, const float* __restrict__ bL,
                unsigned short* __restrict__ outL,
                const unsigned short* __restrict__ WfR, const float* __restrict__ bR,
                unsigned short* __restrict__ outR) {
    constexpr int KB = KIN / 32, NT = NOUT / 16;
    int lane = threadIdx.x & 63;
    int wv = threadIdx.x >> 6;
    int row0 = blockIdx.x * 64 + wv * 16;
    int r16 = lane & 15, kg = lane >> 4;

    int arow = row0 + r16; if (arow >= NN) arow = NN - 1;
    const unsigned short* xrow = X + (size_t)arow * KIN + kg * 8;
    bf16x8 af[KB];
#pragma unroll
    for (int kb = 0; kb < KB; ++kb)
        af[kb] = *reinterpret_cast<const bf16x8*>(xrow + kb * 32);

    const unsigned short* Wf[2] = { WfL, WfR };
    const float* bb[2] = { bL, bR };
    unsigned short* oo[2] = { outL, outR };

#pragma unroll
    for (int w = 0; w < 2; ++w) {
        const bf16x8* wbase = reinterpret_cast<const bf16x8*>(Wf[w]) + lane;
        const float* bw = bb[w];
        unsigned short* ow = oo[w];
#pragma unroll 1
        for (int t = 0; t < NT; ++t) {
            f32x4 acc = {0.f, 0.f, 0.f, 0.f};
            const bf16x8* wp = wbase + (size_t)t * KB * 64;
#pragma unroll
            for (int kb = 0; kb < KB; ++kb)
                acc = __builtin_amdgcn_mfma_f32_16x16x32_bf16(af[kb], wp[kb * 64], acc, 0, 0, 0);
            float bv = bw[t * 16 + r16];
#pragma unroll
            for (int rg = 0; rg < 4; ++rg) {
                int row = row0 + kg * 4 + rg;
                if (row < NN)
                    ow[(size_t)row * NOUT + t * 16 + r16] = f2bf(acc[rg] + bv);
            }
        }
    }
}

// ---------------- GATv2 layer 2 (H=2,C=64): wave/node, 4-edge batch, defer-max ----------------
__global__ __launch_bounds__(256)
void gat2_fused(const unsigned short* __restrict__ xl, const unsigned short* __restrict__ xr,
                const int* __restrict__ rowptr, const int* __restrict__ col,
                const float* __restrict__ att, const float* __restrict__ bias,
                unsigned short* __restrict__ out) {
    constexpr int HC = 128, CPL = 2, GRP = 32;
    int lane = threadIdx.x & 63;
    int node = (blockIdx.x * blockDim.x + threadIdx.x) >> 6;
    if (node >= NN) return;
    int ch0 = lane * CPL;

    float areg[CPL], breg[CPL];
#pragma unroll
    for (int p = 0; p < CPL; ++p) { areg[p] = att[ch0 + p]; breg[p] = bias[ch0 + p]; }

    float xrv[CPL];
    {
        ushort2 u = *reinterpret_cast<const ushort2*>(xr + (size_t)node * HC + ch0);
        xrv[0] = bf2f(u.x); xrv[1] = bf2f(u.y);
    }
    float m = -INFINITY, l = 0.f, acc[CPL];
#pragma unroll
    for (int p = 0; p < CPL; ++p) acc[p] = 0.f;

    int beg = rowptr[node], end = rowptr[node + 1];
    int idx = beg;
    for (; idx + 3 < end; idx += 4) {
        float a[4][CPL];
        float dd[4];
#pragma unroll
        for (int q = 0; q < 4; ++q) {
            int s = col[idx + q];
            ushort2 u = *reinterpret_cast<const ushort2*>(xl + (size_t)s * HC + ch0);
            a[q][0] = bf2f(u.x); a[q][1] = bf2f(u.y);
        }
#pragma unroll
        for (int q = 0; q < 4; ++q) {
            float d = 0.f;
#pragma unroll
            for (int p = 0; p < CPL; ++p) {
                float v = a[q][p] + xrv[p];
                v = v > 0.f ? v : 0.2f * v;
                d = fmaf(v, areg[p], d);
            }
            dd[q] = d;
        }
#pragma unroll
        for (int off = GRP >> 1; off >= 1; off >>= 1) {
#pragma unroll
            for (int q = 0; q < 4; ++q) dd[q] += __shfl_xor(dd[q], off);
        }
        float pmax = fmaxf(fmaxf(dd[0], dd[1]), fmaxf(dd[2], dd[3]));
        if (pmax > m + DMAX_THR) {
            float sc = __expf(m - pmax);
            l *= sc;
#pragma unroll
            for (int p = 0; p < CPL; ++p) acc[p] *= sc;
            m = pmax;
        }
        float p0 = __expf(dd[0] - m), p1 = __expf(dd[1] - m);
        float p2 = __expf(dd[2] - m), p3 = __expf(dd[3] - m);
        l += (p0 + p1) + (p2 + p3);
#pragma unroll
        for (int p = 0; p < CPL; ++p)
            acc[p] += fmaf(p0, a[0][p], p1 * a[1][p]) + fmaf(p2, a[2][p], p3 * a[3][p]);
    }
    for (; idx < end; ++idx) {
        int s0 = col[idx];
        float a0[CPL];
        ushort2 u0 = *reinterpret_cast<const ushort2*>(xl + (size_t)s0 * HC + ch0);
        a0[0] = bf2f(u0.x); a0[1] = bf2f(u0.y);
        float d0 = 0.f;
#pragma unroll
        for (int p = 0; p < CPL; ++p) {
            float v0 = a0[p] + xrv[p];
            v0 = v0 > 0.f ? v0 : 0.2f * v0;
            d0 = fmaf(v0, areg[p], d0);
        }
#pragma unroll
        for (int off = GRP >> 1; off >= 1; off >>= 1) d0 += __shfl_xor(d0, off);
        if (d0 > m + DMAX_THR) {
            float sc = __expf(m - d0);
            l *= sc;
#pragma unroll
            for (int p = 0; p < CPL; ++p) acc[p] *= sc;
            m = d0;
        }
        float p0 = __expf(d0 - m);
        l += p0;
#pragma unroll
        for (int p = 0; p < CPL; ++p)
            acc[p] = fmaf(p0, a0[p], acc[p]);
    }
    float inv = 1.f / (l + 1e-16f);
    float o0 = fmaxf(acc[0] * inv + breg[0], 0.f);
    float o1 = fmaxf(acc[1] * inv + breg[1], 0.f);
    *reinterpret_cast<ushort2*>(out + (size_t)node * HC + ch0) =
        make_ushort2(f2bf(o0), f2bf(o1));
}

// ---------------- GATv2 layer 3 (H=1,C=256): half-wave split ----------------
// Lanes 0-31 / 32-63 run independent online softmaxes over disjoint halves of
// the node's edge list (CPL=8, 16B gathers, 5-level reduce), merged at the end.
__global__ __launch_bounds__(256)
void gat3_fused(const unsigned short* __restrict__ xl, const unsigned short* __restrict__ xr,
                const int* __restrict__ rowptr, const int* __restrict__ col,
                const float* __restrict__ att, const float* __restrict__ bias,
                float* __restrict__ out) {
    int lane = threadIdx.x & 63;
    int half = lane >> 5;
    int node = (blockIdx.x * blockDim.x + threadIdx.x) >> 6;
    if (node >= NN) return;
    int ch0 = (lane & 31) * 8;   // both halves cover channels 0..255

    float areg[8], xrv[8];
    {
        us8 ua = *reinterpret_cast<const us8*>(att + 0 + ch0), ux;  // att is f32! load separately
        (void)ua;
    }
#pragma unroll
    for (int p = 0; p < 8; ++p) areg[p] = att[ch0 + p];
    {
        us8 u = *reinterpret_cast<const us8*>(xr + (size_t)node * 256 + ch0);
#pragma unroll
        for (int p = 0; p < 8; ++p) xrv[p] = bf2f(u[p]);
    }

    float m = -INFINITY, l = 0.f, acc[8];
#pragma unroll
    for (int p = 0; p < 8; ++p) acc[p] = 0.f;

    int beg = rowptr[node], end = rowptr[node + 1];
    int n = end - beg;
    int nh = (n + 1) >> 1;
    int myBeg = beg + (half ? nh : 0);
    int myEnd = half ? end : beg + nh;

    int idx = myBeg;
    for (; idx + 1 < myEnd; idx += 2) {
        int s0 = col[idx], s1 = col[idx + 1];
        float a0[8], a1[8];
        {
            us8 u0 = *reinterpret_cast<const us8*>(xl + (size_t)s0 * 256 + ch0);
            us8 u1 = *reinterpret_cast<const us8*>(xl + (size_t)s1 * 256 + ch0);
#pragma unroll
            for (int p = 0; p < 8; ++p) { a0[p] = bf2f(u0[p]); a1[p] = bf2f(u1[p]); }
        }
        float d0 = 0.f, d1 = 0.f;
#pragma unroll
        for (int p = 0; p < 8; ++p) {
            float v0 = a0[p] + xrv[p];
            float v1 = a1[p] + xrv[p];
            v0 = v0 > 0.f ? v0 : 0.2f * v0;
            v1 = v1 > 0.f ? v1 : 0.2f * v1;
            d0 = fmaf(v0, areg[p], d0);
            d1 = fmaf(v1, areg[p], d1);
        }
#pragma unroll
        for (int off = 16; off >= 1; off >>= 1) {   // stays within 32-lane half
            d0 += __shfl_xor(d0, off);
            d1 += __shfl_xor(d1, off);
        }
        float pmax = fmaxf(d0, d1);
        if (pmax > m + DMAX_THR) {
            float sc = __expf(m - pmax);
            l *= sc;
#pragma unroll
            for (int p = 0; p < 8; ++p) acc[p] *= sc;
            m = pmax;
        }
        float p0 = __expf(d0 - m), p1 = __expf(d1 - m);
        l += p0 + p1;
#pragma unroll
        for (int p = 0; p < 8; ++p)
            acc[p] += fmaf(p0, a0[p], p1 * a1[p]);
    }
    if (idx < myEnd) {
        int s0 = col[idx];
        float a0[8];
        us8 u0 = *reinterpret_cast<const us8*>(xl + (size_t)s0 * 256 + ch0);
#pragma unroll
        for (int p = 0; p < 8; ++p) a0[p] = bf2f(u0[p]);
        float d0 = 0.f;
#pragma unroll
        for (int p = 0; p < 8; ++p) {
            float v0 = a0[p] + xrv[p];
            v0 = v0 > 0.f ? v0 : 0.2f * v0;
            d0 = fmaf(v0, areg[p], d0);
        }
#pragma unroll
        for (int off = 16; off >= 1; off >>= 1) d0 += __shfl_xor(d0, off);
        if (d0 > m + DMAX_THR) {
            float sc = __expf(m - d0);
            l *= sc;
#pragma unroll
            for (int p = 0; p < 8; ++p) acc[p] *= sc;
            m = d0;
        }
        float p0 = __expf(d0 - m);
        l += p0;
#pragma unroll
        for (int p = 0; p < 8; ++p)
            acc[p] = fmaf(p0, a0[p], acc[p]);
    }

    // merge the two halves (softmax-merge); symmetric, both halves get the result
    float mo = __shfl_xor(m, 32);
    float lo = __shfl_xor(l, 32);
    float M = fmaxf(m, mo);
    float sA = __expf(m - M), sB = __expf(mo - M);
    float lsum = l * sA + lo * sB;
    float inv = 1.f / (lsum + 1e-16f);
    float o[8];
#pragma unroll
    for (int p = 0; p < 8; ++p) {
        float ao = __shfl_xor(acc[p], 32);
        o[p] = (acc[p] * sA + ao * sB) * inv + bias[ch0 + p];
    }
    if (half == 0) {
        *reinterpret_cast<float4*>(out + (size_t)node * 256 + ch0) =
            make_float4(o[0], o[1], o[2], o[3]);
        *reinterpret_cast<float4*>(out + (size_t)node * 256 + ch0 + 4) =
            make_float4(o[4], o[5], o[6], o[7]);
    }
}

// ---------------- pool + head MLP ----------------
__global__ __launch_bounds__(64)
void graph_bounds(const int* __restrict__ batch, float* __restrict__ cnt) {
    int g = threadIdx.x;
    if (g >= NG) return;
    int lo = 0, hi = NN;
    while (lo < hi) { int mid = (lo + hi) >> 1; if (batch[mid] < g) lo = mid + 1; else hi = mid; }
    int lo2 = lo, hi2 = NN;
    while (lo2 < hi2) { int mid = (lo2 + hi2) >> 1; if (batch[mid] < g + 1) lo2 = mid + 1; else hi2 = mid; }
    cnt[g] = (float)(lo2 - lo);
}

__global__ __launch_bounds__(256)
void pool_sum(const float* __restrict__ h, const int* __restrict__ batch,
              float* pooled) {
    __shared__ int gb[32];
    int c = threadIdx.x;
    int n0 = blockIdx.x * 32;
    int n1 = min(n0 + 32, NN);
    int cnt = n1 - n0;
    if (c < cnt) gb[c] = batch[n0 + c];
    __syncthreads();
    if (gb[0] == gb[cnt - 1]) {
        float acc = 0.f;
#pragma unroll 4
        for (int i = 0; i < cnt; ++i) acc += h[(size_t)(n0 + i) * 256 + c];
        atomicAdd(&pooled[gb[0] * 256 + c], acc);
    } else {
        int cur = gb[0]; float acc = 0.f;
        for (int i = 0; i < cnt; ++i) {
            int g = gb[i];
            if (g != cur) { atomicAdd(&pooled[cur * 256 + c], acc); acc = 0.f; cur = g; }
            acc += h[(size_t)(n0 + i) * 256 + c];
        }
        atomicAdd(&pooled[cur * 256 + c], acc);
    }
}

__global__ __launch_bounds__(256)
void mlp_ln(const float* __restrict__ pooled, const float* __restrict__ cnt,
            const float* __restrict__ We1, const float* __restrict__ be1,
            const float* __restrict__ We2, const float* __restrict__ be2,
            const float* __restrict__ lng, const float* __restrict__ lnb,
            float* __restrict__ out) {
    __shared__ float p[256];
    __shared__ float t[512];
    __shared__ float red[8];
    int g = blockIdx.x, tid = threadIdx.x;
    p[tid] = pooled[g * 256 + tid] / fmaxf(cnt[g], 1.0f);
    __syncthreads();
    for (int jj = tid; jj < 512; jj += 256) {
        float s = be1[jj];
        for (int k = 0; k < 256; ++k) s = fmaf(p[k], We1[(size_t)k * 512 + jj], s);
        t[jj] = fmaxf(s, 0.f);
    }
    __syncthreads();
    float z = be2[tid];
    for (int k = 0; k < 512; ++k) z = fmaf(t[k], We2[(size_t)k * 256 + tid], z);
    float sv = z, sq = z * z;
#pragma unroll
    for (int off = 32; off >= 1; off >>= 1) {
        sv += __shfl_xor(sv, off);
        sq += __shfl_xor(sq, off);
    }
    int wv = tid >> 6;
    if ((tid & 63) == 0) { red[wv] = sv; red[4 + wv] = sq; }
    __syncthreads();
    float tot = red[0] + red[1] + red[2] + red[3];
    float totq = red[4] + red[5] + red[6] + red[7];
    float mu = tot * (1.f / 256.f);
    float var = totq * (1.f / 256.f) - mu * mu;
    float r = rsqrtf(var + 1e-5f);
    out[g * 256 + tid] = (z - mu) * r * lng[tid] + lnb[tid];
}

extern "C" void kernel_launch(void* const* d_in, const int* in_sizes, int n_in,
                              void* d_out, int out_size, void* d_ws, size_t ws_size,
                              hipStream_t stream) {
    const float* x   = (const float*)d_in[0];
    const int*   ei  = (const int*)d_in[1];
    const int*   bat = (const int*)d_in[2];
    const float *W1l = (const float*)d_in[3], *b1l = (const float*)d_in[4];
    const float *W1r = (const float*)d_in[5], *b1r = (const float*)d_in[6];
    const float *a1  = (const float*)d_in[7], *c1b = (const float*)d_in[8];
    const float *W2l = (const float*)d_in[9],  *b2l = (const float*)d_in[10];
    const float *W2r = (const float*)d_in[11], *b2r = (const float*)d_in[12];
    const float *a2  = (const float*)d_in[13], *c2b = (const float*)d_in[14];
    const float *W3l = (const float*)d_in[15], *b3l = (const float*)d_in[16];
    const float *W3r = (const float*)d_in[17], *b3r = (const float*)d_in[18];
    const float *a3  = (const float*)d_in[19], *c3b = (const float*)d_in[20];
    const float *We1 = (const float*)d_in[21], *be1 = (const float*)d_in[22];
    const float *We2 = (const float*)d_in[23], *be2 = (const float*)d_in[24];
    const float *lng = (const float*)d_in[25], *lnb = (const float*)d_in[26];

    char* base = (char*)d_ws;
    size_t off = 0;
    auto nxt = [&](size_t bytes) { char* p = base + off; off = (off + bytes + 255) & ~(size_t)255; return p; };
    unsigned short* Abuf = (unsigned short*)nxt((size_t)NN * 256 * 2);
    unsigned short* Bbuf = (unsigned short*)nxt((size_t)NN * 256 * 2);
    unsigned short* Hb16 = (unsigned short*)nxt((size_t)NN * 256 * 2);
    float* Hb32 = (float*)nxt((size_t)NN * 256 * 4);
    float* BLR  = (float*)nxt((size_t)NN * 256 * 4);
    int* deg    = (int*)nxt(NN * 4);
    int* rowptr = (int*)nxt((NN + 1) * 4);
    int* cursor = (int*)nxt(NN * 4);
    int* colv   = (int*)nxt((size_t)ETOT * 4);
    int* psum   = (int*)nxt(1024 * 4);
    float* POOL = (float*)nxt(NG * 256 * 4);
    float* CNT  = (float*)nxt(NG * 4);
    unsigned short* Wf2l = (unsigned short*)nxt(256 * 128 * 2);
    unsigned short* Wf2r = (unsigned short*)nxt(256 * 128 * 2);
    unsigned short* Wf3l = (unsigned short*)nxt(128 * 256 * 2);
    unsigned short* Wf3r = (unsigned short*)nxt(128 * 256 * 2);

    const int GEMM_BLKS = (NN + 63) / 64;
    const int NB_NODE = (NN + 3) / 4;   // wave-per-node, 4 waves/block

    // ---- CSR build ----
    hipMemsetAsync(deg, 0, NN * sizeof(int), stream);
    hist_dst<<<(ETOT + 255) / 256, 256, 0, stream>>>(ei, deg);
    scan1<<<SCAN_BLKS, 64, 0, stream>>>(deg, psum);
    scan2<<<1, 1024, 0, stream>>>(psum);
    scan3<<<SCAN_BLKS, 64, 0, stream>>>(deg, psum, rowptr);
    hipMemcpyAsync(cursor, rowptr, NN * sizeof(int), hipMemcpyDeviceToDevice, stream);
    scatter_csr<<<(ETOT + 255) / 256, 256, 0, stream>>>(ei, cursor, colv);

    // ---- weight pre-pack + BLR table ----
    wfrag_all<<<(4 * 32768) / 256, 256, 0, stream>>>(W2l, W2r, W3l, W3r, Wf2l, Wf2r, Wf3l, Wf3r);
    {
        dim3 g(4, (NN + 31) / 32);
        blr_prep<<<g, 256, 0, stream>>>(x, W1r, b1r, b1l, BLR);
    }

    // ---- Layer 1: fully fused from raw x ----
    gat1_fused<<<NB_NODE, 256, 0, stream>>>(x, rowptr, colv, BLR, W1l, b1l, a1, c1b, Hb16);

    // ---- Layer 2: 256 -> (H=2,C=64) ----
    gemm_mfma2<256, 128><<<GEMM_BLKS, 256, 0, stream>>>(Hb16, Wf2l, b2l, Abuf, Wf2r, b2r, Bbuf);
    gat2_fused<<<NB_NODE, 256, 0, stream>>>(Abuf, Bbuf, rowptr, colv, a2, c2b, Hb16);

    // ---- Layer 3: 128 -> (H=1,C=256), concat=False ----
    gemm_mfma2<128, 256><<<GEMM_BLKS, 256, 0, stream>>>(Hb16, Wf3l, b3l, Abuf, Wf3r, b3r, Bbuf);
    gat3_fused<<<NB_NODE, 256, 0, stream>>>(Abuf, Bbuf, rowptr, colv, a3, c3b, Hb32);

    // ---- pool + MLP + LN ----
    hipMemsetAsync(POOL, 0, (size_t)NG * 256 * 4, stream);
    graph_bounds<<<1, 64, 0, stream>>>(bat, CNT);
    pool_sum<<<(NN + 31) / 32, 256, 0, stream>>>(Hb32, bat, POOL);
    mlp_ln<<<NG, 256, 0, stream>>>(POOL, CNT, We1, be1, We2, be2, lng, lnb, (float*)d_out);
}

// Round 12
// 441.060 us; speedup vs baseline: 1.1184x; 1.0717x over previous
//
#include <hip/hip_runtime.h>
#include <hip/hip_bf16.h>
#include <math.h>

#define NN 50000
#define NE0 800000
#define ETOT (NE0 + NN)
#define NG 64
#define SCAN_BLKS ((NN + 63) / 64)   // 782
#define DMAX_THR 8.0f                // defer-max threshold (exp headroom e^8)

typedef _Float16 h2 __attribute__((ext_vector_type(2)));
typedef _Float16 h8 __attribute__((ext_vector_type(8)));
typedef float    f32x4 __attribute__((ext_vector_type(4)));

__device__ __forceinline__ unsigned short f2h(float f) {
    _Float16 h = (_Float16)f;
    return __builtin_bit_cast(unsigned short, h);
}

__device__ __forceinline__ void edge_sd(const int* __restrict__ ei, int e, int& s, int& d) {
    if (e < NE0) { s = ei[e]; d = ei[NE0 + e]; }
    else { s = e - NE0; d = s; }
}

// ---------------- CSR build (by dst) ----------------
__global__ __launch_bounds__(256)
void hist_dst(const int* __restrict__ ei, int* __restrict__ deg) {
    int e = blockIdx.x * blockDim.x + threadIdx.x;
    if (e >= ETOT) return;
    int s, d; edge_sd(ei, e, s, d); (void)s;
    atomicAdd(&deg[d], 1);
}

__global__ __launch_bounds__(64)
void scan1(const int* __restrict__ deg, int* __restrict__ psum) {
    int i = blockIdx.x * 64 + threadIdx.x;
    int v = (i < NN) ? deg[i] : 0;
#pragma unroll
    for (int off = 1; off < 64; off <<= 1) {
        int t = __shfl_up(v, off);
        if ((int)threadIdx.x >= off) v += t;
    }
    if (threadIdx.x == 63) psum[blockIdx.x] = v;
}

__global__ __launch_bounds__(1024)
void scan2(int* __restrict__ psum) {
    __shared__ int sm[1024];
    int t = threadIdx.x;
    sm[t] = (t < SCAN_BLKS) ? psum[t] : 0;
    __syncthreads();
    for (int off = 1; off < 1024; off <<= 1) {
        int v = (t >= off) ? sm[t - off] : 0;
        __syncthreads();
        sm[t] += v;
        __syncthreads();
    }
    if (t < SCAN_BLKS) psum[t] = (t == 0) ? 0 : sm[t - 1];
}

__global__ __launch_bounds__(64)
void scan3(const int* __restrict__ deg, const int* __restrict__ psum,
           int* __restrict__ rowptr, int* __restrict__ cursor) {
    int i = blockIdx.x * 64 + threadIdx.x;
    int v = (i < NN) ? deg[i] : 0;
    int inc = v;
#pragma unroll
    for (int off = 1; off < 64; off <<= 1) {
        int t = __shfl_up(inc, off);
        if ((int)threadIdx.x >= off) inc += t;
    }
    int excl = inc - v + psum[blockIdx.x];
    if (i < NN) { rowptr[i] = excl; cursor[i] = excl; }
    if (i == NN - 1) rowptr[NN] = excl + v;   // == ETOT
}

__global__ __launch_bounds__(256)
void scatter_csr(const int* __restrict__ ei, int* __restrict__ cursor,
                 int* __restrict__ col) {
    int e = blockIdx.x * blockDim.x + threadIdx.x;
    if (e >= ETOT) return;
    int s, d; edge_sd(ei, e, s, d);
    int pos = atomicAdd(&cursor[d], 1);
    col[pos] = s;
}

// ---------------- weight pre-pack (all 4 matrices, one launch, f16) ----------------
__device__ __forceinline__ void wfrag_one(const float* W, unsigned short* Wf,
                                          int r, int KB, int NOUT) {
    int j = r & 7;
    int l = (r >> 3) & 63;
    int rest = r >> 9;
    int kb = rest % KB, t = rest / KB;
    int k = kb * 32 + (l >> 4) * 8 + j;
    int colj = t * 16 + (l & 15);
    Wf[r] = f2h(W[(size_t)k * NOUT + colj]);
}
__global__ __launch_bounds__(256)
void wfrag_all(const float* __restrict__ W2l, const float* __restrict__ W2r,
               const float* __restrict__ W3l, const float* __restrict__ W3r,
               unsigned short* __restrict__ Wf2l, unsigned short* __restrict__ Wf2r,
               unsigned short* __restrict__ Wf3l, unsigned short* __restrict__ Wf3r) {
    int tid = blockIdx.x * 256 + threadIdx.x;   // [0, 4*32768)
    int seg = tid >> 15;
    int r = tid & 32767;
    if (seg == 0)      wfrag_one(W2l, Wf2l, r, 8, 128);
    else if (seg == 1) wfrag_one(W2r, Wf2r, r, 8, 128);
    else if (seg == 2) wfrag_one(W3l, Wf3l, r, 4, 256);
    else               wfrag_one(W3r, Wf3r, r, 4, 256);
}

// ---------------- BLR table: BLR[n,ch] = b1l[ch] + b1r[ch] + sum_k x[n,k] W1r[k,ch] ----------------
__global__ __launch_bounds__(256)
void blr_prep(const float* __restrict__ X, const float* __restrict__ W1r,
              const float* __restrict__ b1r, const float* __restrict__ b1l,
              float* __restrict__ out) {
    int j = blockIdx.x * 64 + (threadIdx.x & 63);
    int row0 = (blockIdx.y * 4 + (threadIdx.x >> 6)) * 8;
    float w0 = W1r[j], w1 = W1r[256 + j], w2 = W1r[512 + j], w3 = W1r[768 + j];
    float bj = b1r[j] + b1l[j];
#pragma unroll
    for (int r = 0; r < 8; ++r) {
        int row = row0 + r;
        if (row >= NN) break;
        float4 xv = *reinterpret_cast<const float4*>(X + (size_t)row * 4);
        out[(size_t)row * 256 + j] =
            fmaf(xv.x, w0, fmaf(xv.y, w1, fmaf(xv.z, w2, fmaf(xv.w, w3, bj))));
    }
}

// ---------------- Layer 1 fully fused (wave/node, 4-edge batch, branchy defer-max) ----------------
__global__ __launch_bounds__(256)
void gat1_fused(const float* __restrict__ x,
                const int* __restrict__ rowptr, const int* __restrict__ col,
                const float* __restrict__ BLR,
                const float* __restrict__ W1l, const float* __restrict__ b1l,
                const float* __restrict__ a1, const float* __restrict__ c1b,
                unsigned short* __restrict__ out) {
    int lane = threadIdx.x & 63;
    int node = (blockIdx.x * blockDim.x + threadIdx.x) >> 6;
    if (node >= NN) return;
    int ch0 = lane * 4;

    float wl[4][4];
#pragma unroll
    for (int k = 0; k < 4; ++k) {
        float4 l4 = *reinterpret_cast<const float4*>(W1l + k * 256 + ch0);
        wl[k][0] = l4.x; wl[k][1] = l4.y; wl[k][2] = l4.z; wl[k][3] = l4.w;
    }
    float4 av  = *reinterpret_cast<const float4*>(a1 + ch0);
    float ar[4] = { av.x, av.y, av.z, av.w };
    float4 blv = *reinterpret_cast<const float4*>(b1l + ch0);
    float4 cbv = *reinterpret_cast<const float4*>(c1b + ch0);
    float obias[4] = { blv.x + cbv.x, blv.y + cbv.y, blv.z + cbv.z, blv.w + cbv.w };

    const float4* x4 = reinterpret_cast<const float4*>(x);

    float4 blrv = *reinterpret_cast<const float4*>(BLR + (size_t)node * 256 + ch0);
    float blr[4] = { blrv.x, blrv.y, blrv.z, blrv.w };

    float m = -INFINITY, l = 0.f;
    float ax = 0.f, ay = 0.f, az = 0.f, aw = 0.f;

    int beg = rowptr[node], end = rowptr[node + 1];
    int idx = beg;
    for (; idx + 3 < end; idx += 4) {
        float4 v[4];
        float dd[4];
#pragma unroll
        for (int q = 0; q < 4; ++q) v[q] = x4[col[idx + q]];
#pragma unroll
        for (int q = 0; q < 4; ++q) {
            float d = 0.f;
#pragma unroll
            for (int p = 0; p < 4; ++p) {
                float u = fmaf(v[q].x, wl[0][p], fmaf(v[q].y, wl[1][p],
                          fmaf(v[q].z, wl[2][p], fmaf(v[q].w, wl[3][p], blr[p]))));
                u = u > 0.f ? u : 0.2f * u;
                d = fmaf(u, ar[p], d);
            }
            dd[q] = d;
        }
#pragma unroll
        for (int off = 8; off >= 1; off >>= 1) {
#pragma unroll
            for (int q = 0; q < 4; ++q) dd[q] += __shfl_xor(dd[q], off);
        }
        float pmax = fmaxf(fmaxf(dd[0], dd[1]), fmaxf(dd[2], dd[3]));
        if (pmax > m + DMAX_THR) {           // rare path
            float sc = __expf(m - pmax);
            l *= sc; ax *= sc; ay *= sc; az *= sc; aw *= sc;
            m = pmax;
        }
        float p0 = __expf(dd[0] - m), p1 = __expf(dd[1] - m);
        float p2 = __expf(dd[2] - m), p3 = __expf(dd[3] - m);
        l += (p0 + p1) + (p2 + p3);
        ax += fmaf(p0, v[0].x, p1 * v[1].x) + fmaf(p2, v[2].x, p3 * v[3].x);
        ay += fmaf(p0, v[0].y, p1 * v[1].y) + fmaf(p2, v[2].y, p3 * v[3].y);
        az += fmaf(p0, v[0].z, p1 * v[1].z) + fmaf(p2, v[2].z, p3 * v[3].z);
        aw += fmaf(p0, v[0].w, p1 * v[1].w) + fmaf(p2, v[2].w, p3 * v[3].w);
    }
    for (; idx < end; ++idx) {
        float4 v0 = x4[col[idx]];
        float d0 = 0.f;
#pragma unroll
        for (int p = 0; p < 4; ++p) {
            float u0 = fmaf(v0.x, wl[0][p], fmaf(v0.y, wl[1][p],
                       fmaf(v0.z, wl[2][p], fmaf(v0.w, wl[3][p], blr[p]))));
            u0 = u0 > 0.f ? u0 : 0.2f * u0;
            d0 = fmaf(u0, ar[p], d0);
        }
#pragma unroll
        for (int off = 8; off >= 1; off >>= 1) d0 += __shfl_xor(d0, off);
        if (d0 > m + DMAX_THR) {
            float sc = __expf(m - d0);
            l *= sc; ax *= sc; ay *= sc; az *= sc; aw *= sc;
            m = d0;
        }
        float p0 = __expf(d0 - m);
        l += p0;
        ax = fmaf(p0, v0.x, ax);
        ay = fmaf(p0, v0.y, ay);
        az = fmaf(p0, v0.z, az);
        aw = fmaf(p0, v0.w, aw);
    }
    float inv = 1.f / (l + 1e-16f);
    unsigned short o[4];
#pragma unroll
    for (int p = 0; p < 4; ++p) {
        float v = fmaf(ax, wl[0][p], fmaf(ay, wl[1][p],
                  fmaf(az, wl[2][p], aw * wl[3][p]))) * inv + obias[p];
        o[p] = f2h(fmaxf(v, 0.f));
    }
    *reinterpret_cast<ushort4*>(out + (size_t)node * 256 + ch0) =
        make_ushort4(o[0], o[1], o[2], o[3]);
}

// ---------------- fused MFMA GEMM (f16) ----------------
template<int KIN, int NOUT>
__global__ __launch_bounds__(256)
void gemm_mfma2(const unsigned short* __restrict__ X,
                const unsigned short* __restrict__ WfL, const float* __restrict__ bL,
                unsigned short* __restrict__ outL,
                const unsigned short* __restrict__ WfR, const float* __restrict__ bR,
                unsigned short* __restrict__ outR) {
    constexpr int KB = KIN / 32, NT = NOUT / 16;
    int lane = threadIdx.x & 63;
    int wv = threadIdx.x >> 6;
    int row0 = blockIdx.x * 64 + wv * 16;
    int r16 = lane & 15, kg = lane >> 4;

    int arow = row0 + r16; if (arow >= NN) arow = NN - 1;
    const unsigned short* xrow = X + (size_t)arow * KIN + kg * 8;
    h8 af[KB];
#pragma unroll
    for (int kb = 0; kb < KB; ++kb)
        af[kb] = *reinterpret_cast<const h8*>(xrow + kb * 32);

    const unsigned short* Wf[2] = { WfL, WfR };
    const float* bb[2] = { bL, bR };
    unsigned short* oo[2] = { outL, outR };

#pragma unroll
    for (int w = 0; w < 2; ++w) {
        const h8* wbase = reinterpret_cast<const h8*>(Wf[w]) + lane;
        const float* bw = bb[w];
        unsigned short* ow = oo[w];
#pragma unroll 1
        for (int t = 0; t < NT; ++t) {
            f32x4 acc = {0.f, 0.f, 0.f, 0.f};
            const h8* wp = wbase + (size_t)t * KB * 64;
#pragma unroll
            for (int kb = 0; kb < KB; ++kb)
                acc = __builtin_amdgcn_mfma_f32_16x16x32_f16(af[kb], wp[kb * 64], acc, 0, 0, 0);
            float bv = bw[t * 16 + r16];
#pragma unroll
            for (int rg = 0; rg < 4; ++rg) {
                int row = row0 + kg * 4 + rg;
                if (row < NN)
                    ow[(size_t)row * NOUT + t * 16 + r16] = f2h(acc[rg] + bv);
            }
        }
    }
}

// ---------------- GATv2 layer 2 (H=2,C=64): half-wave split, f16 packed math ----------------
__global__ __launch_bounds__(256)
void gat2_fused(const unsigned short* __restrict__ xl, const unsigned short* __restrict__ xr,
                const int* __restrict__ rowptr, const int* __restrict__ col,
                const float* __restrict__ att, const float* __restrict__ bias,
                unsigned short* __restrict__ out) {
    constexpr int HC = 128;
    int lane = threadIdx.x & 63;
    int half = lane >> 5;
    int l32 = lane & 31;
    int node = (blockIdx.x * blockDim.x + threadIdx.x) >> 6;
    if (node >= NN) return;
    int ch0 = l32 * 4;   // lanes 0-15: head0, 16-31: head1 (per half)

    const h2 c02 = (h2){(_Float16)0.2f, (_Float16)0.2f};
    h2 a2[2];
#pragma unroll
    for (int p = 0; p < 2; ++p)
        a2[p] = (h2){(_Float16)att[ch0 + 2*p], (_Float16)att[ch0 + 2*p + 1]};
    const h2* xrp = reinterpret_cast<const h2*>(xr + (size_t)node * HC + ch0);
    h2 xr2[2] = { xrp[0], xrp[1] };

    float m = -INFINITY, l = 0.f, acc[4] = {0.f, 0.f, 0.f, 0.f};

    int beg = rowptr[node], end = rowptr[node + 1];
    int n = end - beg;
    int nh = (n + 1) >> 1;
    int idx = beg + (half ? nh : 0);
    int myEnd = half ? end : beg + nh;

    for (; idx + 1 < myEnd; idx += 2) {
        int s0 = col[idx], s1 = col[idx + 1];
        const h2* p0 = reinterpret_cast<const h2*>(xl + (size_t)s0 * HC + ch0);
        const h2* p1 = reinterpret_cast<const h2*>(xl + (size_t)s1 * HC + ch0);
        h2 e0[2] = { p0[0], p0[1] };
        h2 e1[2] = { p1[0], p1[1] };
        float d0 = 0.f, d1 = 0.f;
#pragma unroll
        for (int p = 0; p < 2; ++p) {
            h2 u0 = e0[p] + xr2[p];
            h2 u1 = e1[p] + xr2[p];
            u0 = __builtin_elementwise_max(u0, u0 * c02);
            u1 = __builtin_elementwise_max(u1, u1 * c02);
            d0 = __builtin_amdgcn_fdot2(u0, a2[p], d0, false);
            d1 = __builtin_amdgcn_fdot2(u1, a2[p], d1, false);
        }
#pragma unroll
        for (int off = 8; off >= 1; off >>= 1) {   // 16-lane head group, stays in half
            d0 += __shfl_xor(d0, off);
            d1 += __shfl_xor(d1, off);
        }
        float pmax = fmaxf(d0, d1);
        if (pmax > m + DMAX_THR) {
            float sc = __expf(m - pmax);
            l *= sc;
#pragma unroll
            for (int p = 0; p < 4; ++p) acc[p] *= sc;
            m = pmax;
        }
        float pw0 = __expf(d0 - m), pw1 = __expf(d1 - m);
        l += pw0 + pw1;
#pragma unroll
        for (int p = 0; p < 4; ++p)
            acc[p] = fmaf(pw0, (float)e0[p >> 1][p & 1],
                     fmaf(pw1, (float)e1[p >> 1][p & 1], acc[p]));
    }
    if (idx < myEnd) {
        int s0 = col[idx];
        const h2* p0 = reinterpret_cast<const h2*>(xl + (size_t)s0 * HC + ch0);
        h2 e0[2] = { p0[0], p0[1] };
        float d0 = 0.f;
#pragma unroll
        for (int p = 0; p < 2; ++p) {
            h2 u0 = e0[p] + xr2[p];
            u0 = __builtin_elementwise_max(u0, u0 * c02);
            d0 = __builtin_amdgcn_fdot2(u0, a2[p], d0, false);
        }
#pragma unroll
        for (int off = 8; off >= 1; off >>= 1) d0 += __shfl_xor(d0, off);
        if (d0 > m + DMAX_THR) {
            float sc = __expf(m - d0);
            l *= sc;
#pragma unroll
            for (int p = 0; p < 4; ++p) acc[p] *= sc;
            m = d0;
        }
        float pw0 = __expf(d0 - m);
        l += pw0;
#pragma unroll
        for (int p = 0; p < 4; ++p)
            acc[p] = fmaf(pw0, (float)e0[p >> 1][p & 1], acc[p]);
    }

    // merge halves (same channels/head, disjoint edges)
    float mo = __shfl_xor(m, 32);
    float lo = __shfl_xor(l, 32);
    float M = fmaxf(m, mo);
    float sA = __expf(m - M), sB = __expf(mo - M);
    float lsum = l * sA + lo * sB;
    float inv = 1.f / (lsum + 1e-16f);
    unsigned short o[4];
#pragma unroll
    for (int p = 0; p < 4; ++p) {
        float ao = __shfl_xor(acc[p], 32);
        float v = (acc[p] * sA + ao * sB) * inv + bias[ch0 + p];
        o[p] = f2h(fmaxf(v, 0.f));
    }
    if (half == 0)
        *reinterpret_cast<ushort4*>(out + (size_t)node * HC + ch0) =
            make_ushort4(o[0], o[1], o[2], o[3]);
}

// ---------------- GATv2 layer 3 (H=1,C=256): half-wave split, f16 packed math ----------------
__global__ __launch_bounds__(256)
void gat3_fused(const unsigned short* __restrict__ xl, const unsigned short* __restrict__ xr,
                const int* __restrict__ rowptr, const int* __restrict__ col,
                const float* __restrict__ att, const float* __restrict__ bias,
                float* __restrict__ out) {
    int lane = threadIdx.x & 63;
    int half = lane >> 5;
    int node = (blockIdx.x * blockDim.x + threadIdx.x) >> 6;
    if (node >= NN) return;
    int ch0 = (lane & 31) * 8;

    const h2 c02 = (h2){(_Float16)0.2f, (_Float16)0.2f};
    h2 a2[4];
#pragma unroll
    for (int p = 0; p < 4; ++p)
        a2[p] = (h2){(_Float16)att[ch0 + 2*p], (_Float16)att[ch0 + 2*p + 1]};
    const h2* xrp = reinterpret_cast<const h2*>(xr + (size_t)node * 256 + ch0);
    h2 xr2[4] = { xrp[0], xrp[1], xrp[2], xrp[3] };

    float m = -INFINITY, l = 0.f, acc[8];
#pragma unroll
    for (int p = 0; p < 8; ++p) acc[p] = 0.f;

    int beg = rowptr[node], end = rowptr[node + 1];
    int n = end - beg;
    int nh = (n + 1) >> 1;
    int idx = beg + (half ? nh : 0);
    int myEnd = half ? end : beg + nh;

    for (; idx + 1 < myEnd; idx += 2) {
        int s0 = col[idx], s1 = col[idx + 1];
        const h2* p0 = reinterpret_cast<const h2*>(xl + (size_t)s0 * 256 + ch0);
        const h2* p1 = reinterpret_cast<const h2*>(xl + (size_t)s1 * 256 + ch0);
        h2 e0[4] = { p0[0], p0[1], p0[2], p0[3] };
        h2 e1[4] = { p1[0], p1[1], p1[2], p1[3] };
        float d0 = 0.f, d1 = 0.f;
#pragma unroll
        for (int p = 0; p < 4; ++p) {
            h2 u0 = e0[p] + xr2[p];
            h2 u1 = e1[p] + xr2[p];
            u0 = __builtin_elementwise_max(u0, u0 * c02);
            u1 = __builtin_elementwise_max(u1, u1 * c02);
            d0 = __builtin_amdgcn_fdot2(u0, a2[p], d0, false);
            d1 = __builtin_amdgcn_fdot2(u1, a2[p], d1, false);
        }
#pragma unroll
        for (int off = 16; off >= 1; off >>= 1) {   // stays within 32-lane half
            d0 += __shfl_xor(d0, off);
            d1 += __shfl_xor(d1, off);
        }
        float pmax = fmaxf(d0, d1);
        if (pmax > m + DMAX_THR) {
            float sc = __expf(m - pmax);
            l *= sc;
#pragma unroll
            for (int p = 0; p < 8; ++p) acc[p] *= sc;
            m = pmax;
        }
        float pw0 = __expf(d0 - m), pw1 = __expf(d1 - m);
        l += pw0 + pw1;
#pragma unroll
        for (int p = 0; p < 8; ++p)
            acc[p] = fmaf(pw0, (float)e0[p >> 1][p & 1],
                     fmaf(pw1, (float)e1[p >> 1][p & 1], acc[p]));
    }
    if (idx < myEnd) {
        int s0 = col[idx];
        const h2* p0 = reinterpret_cast<const h2*>(xl + (size_t)s0 * 256 + ch0);
        h2 e0[4] = { p0[0], p0[1], p0[2], p0[3] };
        float d0 = 0.f;
#pragma unroll
        for (int p = 0; p < 4; ++p) {
            h2 u0 = e0[p] + xr2[p];
            u0 = __builtin_elementwise_max(u0, u0 * c02);
            d0 = __builtin_amdgcn_fdot2(u0, a2[p], d0, false);
        }
#pragma unroll
        for (int off = 16; off >= 1; off >>= 1) d0 += __shfl_xor(d0, off);
        if (d0 > m + DMAX_THR) {
            float sc = __expf(m - d0);
            l *= sc;
#pragma unroll
            for (int p = 0; p < 8; ++p) acc[p] *= sc;
            m = d0;
        }
        float pw0 = __expf(d0 - m);
        l += pw0;
#pragma unroll
        for (int p = 0; p < 8; ++p)
            acc[p] = fmaf(pw0, (float)e0[p >> 1][p & 1], acc[p]);
    }

    // merge the two halves
    float mo = __shfl_xor(m, 32);
    float lo = __shfl_xor(l, 32);
    float M = fmaxf(m, mo);
    float sA = __expf(m - M), sB = __expf(mo - M);
    float lsum = l * sA + lo * sB;
    float inv = 1.f / (lsum + 1e-16f);
    float o[8];
#pragma unroll
    for (int p = 0; p < 8; ++p) {
        float ao = __shfl_xor(acc[p], 32);
        o[p] = (acc[p] * sA + ao * sB) * inv + bias[ch0 + p];
    }
    if (half == 0) {
        *reinterpret_cast<float4*>(out + (size_t)node * 256 + ch0) =
            make_float4(o[0], o[1], o[2], o[3]);
        *reinterpret_cast<float4*>(out + (size_t)node * 256 + ch0 + 4) =
            make_float4(o[4], o[5], o[6], o[7]);
    }
}

// ---------------- pool + head MLP ----------------
// zeroes POOL and computes per-graph counts (batch sorted -> binary search)
__global__ __launch_bounds__(256)
void graph_bounds(const int* __restrict__ batch, float* __restrict__ cnt,
                  float* __restrict__ pooled) {
    int g = blockIdx.x, tid = threadIdx.x;
    pooled[g * 256 + tid] = 0.f;
    if (tid == 0) {
        int lo = 0, hi = NN;
        while (lo < hi) { int mid = (lo + hi) >> 1; if (batch[mid] < g) lo = mid + 1; else hi = mid; }
        int lo2 = lo, hi2 = NN;
        while (lo2 < hi2) { int mid = (lo2 + hi2) >> 1; if (batch[mid] < g + 1) lo2 = mid + 1; else hi2 = mid; }
        cnt[g] = (float)(lo2 - lo);
    }
}

__global__ __launch_bounds__(256)
void pool_sum(const float* __restrict__ h, const int* __restrict__ batch,
              float* pooled) {
    __shared__ int gb[32];
    int c = threadIdx.x;
    int n0 = blockIdx.x * 32;
    int n1 = min(n0 + 32, NN);
    int cnt = n1 - n0;
    if (c < cnt) gb[c] = batch[n0 + c];
    __syncthreads();
    if (gb[0] == gb[cnt - 1]) {
        float acc = 0.f;
#pragma unroll 4
        for (int i = 0; i < cnt; ++i) acc += h[(size_t)(n0 + i) * 256 + c];
        atomicAdd(&pooled[gb[0] * 256 + c], acc);
    } else {
        int cur = gb[0]; float acc = 0.f;
        for (int i = 0; i < cnt; ++i) {
            int g = gb[i];
            if (g != cur) { atomicAdd(&pooled[cur * 256 + c], acc); acc = 0.f; cur = g; }
            acc += h[(size_t)(n0 + i) * 256 + c];
        }
        atomicAdd(&pooled[cur * 256 + c], acc);
    }
}

__global__ __launch_bounds__(256)
void mlp_ln(const float* __restrict__ pooled, const float* __restrict__ cnt,
            const float* __restrict__ We1, const float* __restrict__ be1,
            const float* __restrict__ We2, const float* __restrict__ be2,
            const float* __restrict__ lng, const float* __restrict__ lnb,
            float* __restrict__ out) {
    __shared__ float p[256];
    __shared__ float t[512];
    __shared__ float red[8];
    int g = blockIdx.x, tid = threadIdx.x;
    p[tid] = pooled[g * 256 + tid] / fmaxf(cnt[g], 1.0f);
    __syncthreads();
    for (int jj = tid; jj < 512; jj += 256) {
        float s = be1[jj];
        for (int k = 0; k < 256; ++k) s = fmaf(p[k], We1[(size_t)k * 512 + jj], s);
        t[jj] = fmaxf(s, 0.f);
    }
    __syncthreads();
    float z = be2[tid];
    for (int k = 0; k < 512; ++k) z = fmaf(t[k], We2[(size_t)k * 256 + tid], z);
    float sv = z, sq = z * z;
#pragma unroll
    for (int off = 32; off >= 1; off >>= 1) {
        sv += __shfl_xor(sv, off);
        sq += __shfl_xor(sq, off);
    }
    int wv = tid >> 6;
    if ((tid & 63) == 0) { red[wv] = sv; red[4 + wv] = sq; }
    __syncthreads();
    float tot = red[0] + red[1] + red[2] + red[3];
    float totq = red[4] + red[5] + red[6] + red[7];
    float mu = tot * (1.f / 256.f);
    float var = totq * (1.f / 256.f) - mu * mu;
    float r = rsqrtf(var + 1e-5f);
    out[g * 256 + tid] = (z - mu) * r * lng[tid] + lnb[tid];
}

extern "C" void kernel_launch(void* const* d_in, const int* in_sizes, int n_in,
                              void* d_out, int out_size, void* d_ws, size_t ws_size,
                              hipStream_t stream) {
    const float* x   = (const float*)d_in[0];
    const int*   ei  = (const int*)d_in[1];
    const int*   bat = (const int*)d_in[2];
    const float *W1l = (const float*)d_in[3], *b1l = (const float*)d_in[4];
    const float *W1r = (const float*)d_in[5], *b1r = (const float*)d_in[6];
    const float *a1  = (const float*)d_in[7], *c1b = (const float*)d_in[8];
    const float *W2l = (const float*)d_in[9],  *b2l = (const float*)d_in[10];
    const float *W2r = (const float*)d_in[11], *b2r = (const float*)d_in[12];
    const float *a2  = (const float*)d_in[13], *c2b = (const float*)d_in[14];
    const float *W3l = (const float*)d_in[15], *b3l = (const float*)d_in[16];
    const float *W3r = (const float*)d_in[17], *b3r = (const float*)d_in[18];
    const float *a3  = (const float*)d_in[19], *c3b = (const float*)d_in[20];
    const float *We1 = (const float*)d_in[21], *be1 = (const float*)d_in[22];
    const float *We2 = (const float*)d_in[23], *be2 = (const float*)d_in[24];
    const float *lng = (const float*)d_in[25], *lnb = (const float*)d_in[26];

    char* base = (char*)d_ws;
    size_t off = 0;
    auto nxt = [&](size_t bytes) { char* p = base + off; off = (off + bytes + 255) & ~(size_t)255; return p; };
    unsigned short* Abuf = (unsigned short*)nxt((size_t)NN * 256 * 2);
    unsigned short* Bbuf = (unsigned short*)nxt((size_t)NN * 256 * 2);
    unsigned short* Hb16 = (unsigned short*)nxt((size_t)NN * 256 * 2);
    float* Hb32 = (float*)nxt((size_t)NN * 256 * 4);
    float* BLR  = (float*)nxt((size_t)NN * 256 * 4);
    int* deg    = (int*)nxt(NN * 4);
    int* rowptr = (int*)nxt((NN + 1) * 4);
    int* cursor = (int*)nxt(NN * 4);
    int* colv   = (int*)nxt((size_t)ETOT * 4);
    int* psum   = (int*)nxt(1024 * 4);
    float* POOL = (float*)nxt(NG * 256 * 4);
    float* CNT  = (float*)nxt(NG * 4);
    unsigned short* Wf2l = (unsigned short*)nxt(256 * 128 * 2);
    unsigned short* Wf2r = (unsigned short*)nxt(256 * 128 * 2);
    unsigned short* Wf3l = (unsigned short*)nxt(128 * 256 * 2);
    unsigned short* Wf3r = (unsigned short*)nxt(128 * 256 * 2);

    const int GEMM_BLKS = (NN + 63) / 64;
    const int NB_NODE = (NN + 3) / 4;   // wave-per-node, 4 waves/block

    // ---- CSR build ----
    hipMemsetAsync(deg, 0, NN * sizeof(int), stream);
    hist_dst<<<(ETOT + 255) / 256, 256, 0, stream>>>(ei, deg);
    scan1<<<SCAN_BLKS, 64, 0, stream>>>(deg, psum);
    scan2<<<1, 1024, 0, stream>>>(psum);
    scan3<<<SCAN_BLKS, 64, 0, stream>>>(deg, psum, rowptr, cursor);
    scatter_csr<<<(ETOT + 255) / 256, 256, 0, stream>>>(ei, cursor, colv);

    // ---- weight pre-pack + BLR table ----
    wfrag_all<<<(4 * 32768) / 256, 256, 0, stream>>>(W2l, W2r, W3l, W3r, Wf2l, Wf2r, Wf3l, Wf3r);
    {
        dim3 g(4, (NN + 31) / 32);
        blr_prep<<<g, 256, 0, stream>>>(x, W1r, b1r, b1l, BLR);
    }

    // ---- Layer 1: fully fused from raw x ----
    gat1_fused<<<NB_NODE, 256, 0, stream>>>(x, rowptr, colv, BLR, W1l, b1l, a1, c1b, Hb16);

    // ---- Layer 2: 256 -> (H=2,C=64) ----
    gemm_mfma2<256, 128><<<GEMM_BLKS, 256, 0, stream>>>(Hb16, Wf2l, b2l, Abuf, Wf2r, b2r, Bbuf);
    gat2_fused<<<NB_NODE, 256, 0, stream>>>(Abuf, Bbuf, rowptr, colv, a2, c2b, Hb16);

    // ---- Layer 3: 128 -> (H=1,C=256), concat=False ----
    gemm_mfma2<128, 256><<<GEMM_BLKS, 256, 0, stream>>>(Hb16, Wf3l, b3l, Abuf, Wf3r, b3r, Bbuf);
    gat3_fused<<<NB_NODE, 256, 0, stream>>>(Abuf, Bbuf, rowptr, colv, a3, c3b, Hb32);

    // ---- pool + MLP + LN ----
    graph_bounds<<<NG, 256, 0, stream>>>(bat, CNT, POOL);
    pool_sum<<<(NN + 31) / 32, 256, 0, stream>>>(Hb32, bat, POOL);
    mlp_ln<<<NG, 256, 0, stream>>>(POOL, CNT, We1, be1, We2, be2, lng, lnb, (float*)d_out);
}

// Round 13
// 416.682 us; speedup vs baseline: 1.1839x; 1.0585x over previous
//
#include <hip/hip_runtime.h>
#include <hip/hip_bf16.h>
#include <math.h>

#define NN 50000
#define NE0 800000
#define ETOT (NE0 + NN)
#define NG 64
#define SCAN_BLKS ((NN + 63) / 64)   // 782
#define DMAX_THR 8.0f                // defer-max threshold (exp headroom e^8)

typedef _Float16 h2 __attribute__((ext_vector_type(2)));
typedef _Float16 h8 __attribute__((ext_vector_type(8)));
typedef float    f32x4 __attribute__((ext_vector_type(4)));
typedef unsigned short us8 __attribute__((ext_vector_type(8)));

__device__ __forceinline__ unsigned short f2h(float f) {
    _Float16 h = (_Float16)f;
    return __builtin_bit_cast(unsigned short, h);
}

__device__ __forceinline__ void edge_sd(const int* __restrict__ ei, int e, int& s, int& d) {
    if (e < NE0) { s = ei[e]; d = ei[NE0 + e]; }
    else { s = e - NE0; d = s; }
}

// ---------------- CSR build (by dst) ----------------
__global__ __launch_bounds__(256)
void hist_dst(const int* __restrict__ ei, int* __restrict__ deg) {
    int e = blockIdx.x * blockDim.x + threadIdx.x;
    if (e >= ETOT) return;
    int s, d; edge_sd(ei, e, s, d); (void)s;
    atomicAdd(&deg[d], 1);
}

__global__ __launch_bounds__(64)
void scan1(const int* __restrict__ deg, int* __restrict__ psum) {
    int i = blockIdx.x * 64 + threadIdx.x;
    int v = (i < NN) ? deg[i] : 0;
#pragma unroll
    for (int off = 1; off < 64; off <<= 1) {
        int t = __shfl_up(v, off);
        if ((int)threadIdx.x >= off) v += t;
    }
    if (threadIdx.x == 63) psum[blockIdx.x] = v;
}

__global__ __launch_bounds__(1024)
void scan2(int* __restrict__ psum) {
    __shared__ int sm[1024];
    int t = threadIdx.x;
    sm[t] = (t < SCAN_BLKS) ? psum[t] : 0;
    __syncthreads();
    for (int off = 1; off < 1024; off <<= 1) {
        int v = (t >= off) ? sm[t - off] : 0;
        __syncthreads();
        sm[t] += v;
        __syncthreads();
    }
    if (t < SCAN_BLKS) psum[t] = (t == 0) ? 0 : sm[t - 1];
}

__global__ __launch_bounds__(64)
void scan3(const int* __restrict__ deg, const int* __restrict__ psum,
           int* __restrict__ rowptr, int* __restrict__ cursor) {
    int i = blockIdx.x * 64 + threadIdx.x;
    int v = (i < NN) ? deg[i] : 0;
    int inc = v;
#pragma unroll
    for (int off = 1; off < 64; off <<= 1) {
        int t = __shfl_up(inc, off);
        if ((int)threadIdx.x >= off) inc += t;
    }
    int excl = inc - v + psum[blockIdx.x];
    if (i < NN) { rowptr[i] = excl; cursor[i] = excl; }
    if (i == NN - 1) rowptr[NN] = excl + v;   // == ETOT
}

__global__ __launch_bounds__(256)
void scatter_csr(const int* __restrict__ ei, int* __restrict__ cursor,
                 int* __restrict__ col) {
    int e = blockIdx.x * blockDim.x + threadIdx.x;
    if (e >= ETOT) return;
    int s, d; edge_sd(ei, e, s, d);
    int pos = atomicAdd(&cursor[d], 1);
    col[pos] = s;
}

// ---------------- weight pre-pack (all 4 matrices, one launch, f16) ----------------
__device__ __forceinline__ void wfrag_one(const float* W, unsigned short* Wf,
                                          int r, int KB, int NOUT) {
    int j = r & 7;
    int l = (r >> 3) & 63;
    int rest = r >> 9;
    int kb = rest % KB, t = rest / KB;
    int k = kb * 32 + (l >> 4) * 8 + j;
    int colj = t * 16 + (l & 15);
    Wf[r] = f2h(W[(size_t)k * NOUT + colj]);
}
__global__ __launch_bounds__(256)
void wfrag_all(const float* __restrict__ W2l, const float* __restrict__ W2r,
               const float* __restrict__ W3l, const float* __restrict__ W3r,
               unsigned short* __restrict__ Wf2l, unsigned short* __restrict__ Wf2r,
               unsigned short* __restrict__ Wf3l, unsigned short* __restrict__ Wf3r) {
    int tid = blockIdx.x * 256 + threadIdx.x;   // [0, 4*32768)
    int seg = tid >> 15;
    int r = tid & 32767;
    if (seg == 0)      wfrag_one(W2l, Wf2l, r, 8, 128);
    else if (seg == 1) wfrag_one(W2r, Wf2r, r, 8, 128);
    else if (seg == 2) wfrag_one(W3l, Wf3l, r, 4, 256);
    else               wfrag_one(W3r, Wf3r, r, 4, 256);
}

// ---------------- Q/R tables: Q = x@W1l + b1l, R = x@W1r + b1r (f16) ----------------
__global__ __launch_bounds__(256)
void qr_prep(const float* __restrict__ X,
             const float* __restrict__ W1l, const float* __restrict__ b1l,
             const float* __restrict__ W1r, const float* __restrict__ b1r,
             unsigned short* __restrict__ Q, unsigned short* __restrict__ R) {
    int j = blockIdx.x * 64 + (threadIdx.x & 63);
    int row0 = (blockIdx.y * 4 + (threadIdx.x >> 6)) * 8;
    float l0 = W1l[j], l1 = W1l[256 + j], l2 = W1l[512 + j], l3 = W1l[768 + j];
    float r0 = W1r[j], r1 = W1r[256 + j], r2 = W1r[512 + j], r3 = W1r[768 + j];
    float bl = b1l[j], br = b1r[j];
#pragma unroll
    for (int r = 0; r < 8; ++r) {
        int row = row0 + r;
        if (row >= NN) break;
        float4 xv = *reinterpret_cast<const float4*>(X + (size_t)row * 4);
        float q = fmaf(xv.x, l0, fmaf(xv.y, l1, fmaf(xv.z, l2, fmaf(xv.w, l3, bl))));
        float rr = fmaf(xv.x, r0, fmaf(xv.y, r1, fmaf(xv.z, r2, fmaf(xv.w, r3, br))));
        Q[(size_t)row * 256 + j] = f2h(q);
        R[(size_t)row * 256 + j] = f2h(rr);
    }
}

// ---------------- GATv2 layer 1 (H=4,C=64): half-wave split, f16 packed math ----------------
// 32-lane half covers 256 ch (8/lane); head = 8-lane group (3-level reduce);
// per-head-group online softmax; halves process disjoint edge ranges, merged at end.
__global__ __launch_bounds__(256)
void gat1_fused(const unsigned short* __restrict__ Q, const unsigned short* __restrict__ R,
                const int* __restrict__ rowptr, const int* __restrict__ col,
                const float* __restrict__ att, const float* __restrict__ bias,
                unsigned short* __restrict__ out) {
    int lane = threadIdx.x & 63;
    int half = lane >> 5;
    int node = (blockIdx.x * blockDim.x + threadIdx.x) >> 6;
    if (node >= NN) return;
    int ch0 = (lane & 31) * 8;

    const h2 c02 = (h2){(_Float16)0.2f, (_Float16)0.2f};
    h2 a2[4];
#pragma unroll
    for (int p = 0; p < 4; ++p)
        a2[p] = (h2){(_Float16)att[ch0 + 2*p], (_Float16)att[ch0 + 2*p + 1]};
    const h2* rp = reinterpret_cast<const h2*>(R + (size_t)node * 256 + ch0);
    h2 r2[4] = { rp[0], rp[1], rp[2], rp[3] };

    float m = -INFINITY, l = 0.f, acc[8];
#pragma unroll
    for (int p = 0; p < 8; ++p) acc[p] = 0.f;

    int beg = rowptr[node], end = rowptr[node + 1];
    int n = end - beg;
    int nh = (n + 1) >> 1;
    int idx = beg + (half ? nh : 0);
    int myEnd = half ? end : beg + nh;

    for (; idx + 1 < myEnd; idx += 2) {
        int s0 = col[idx], s1 = col[idx + 1];
        const h2* p0 = reinterpret_cast<const h2*>(Q + (size_t)s0 * 256 + ch0);
        const h2* p1 = reinterpret_cast<const h2*>(Q + (size_t)s1 * 256 + ch0);
        h2 e0[4] = { p0[0], p0[1], p0[2], p0[3] };
        h2 e1[4] = { p1[0], p1[1], p1[2], p1[3] };
        float d0 = 0.f, d1 = 0.f;
#pragma unroll
        for (int p = 0; p < 4; ++p) {
            h2 u0 = e0[p] + r2[p];
            h2 u1 = e1[p] + r2[p];
            u0 = __builtin_elementwise_max(u0, u0 * c02);
            u1 = __builtin_elementwise_max(u1, u1 * c02);
            d0 = __builtin_amdgcn_fdot2(u0, a2[p], d0, false);
            d1 = __builtin_amdgcn_fdot2(u1, a2[p], d1, false);
        }
#pragma unroll
        for (int off = 4; off >= 1; off >>= 1) {   // 8-lane head group
            d0 += __shfl_xor(d0, off);
            d1 += __shfl_xor(d1, off);
        }
        float pmax = fmaxf(d0, d1);
        if (pmax > m + DMAX_THR) {                 // per-head-group rare path
            float sc = __expf(m - pmax);
            l *= sc;
#pragma unroll
            for (int p = 0; p < 8; ++p) acc[p] *= sc;
            m = pmax;
        }
        float pw0 = __expf(d0 - m), pw1 = __expf(d1 - m);
        l += pw0 + pw1;
#pragma unroll
        for (int p = 0; p < 8; ++p)
            acc[p] = fmaf(pw0, (float)e0[p >> 1][p & 1],
                     fmaf(pw1, (float)e1[p >> 1][p & 1], acc[p]));
    }
    if (idx < myEnd) {
        int s0 = col[idx];
        const h2* p0 = reinterpret_cast<const h2*>(Q + (size_t)s0 * 256 + ch0);
        h2 e0[4] = { p0[0], p0[1], p0[2], p0[3] };
        float d0 = 0.f;
#pragma unroll
        for (int p = 0; p < 4; ++p) {
            h2 u0 = e0[p] + r2[p];
            u0 = __builtin_elementwise_max(u0, u0 * c02);
            d0 = __builtin_amdgcn_fdot2(u0, a2[p], d0, false);
        }
#pragma unroll
        for (int off = 4; off >= 1; off >>= 1) d0 += __shfl_xor(d0, off);
        if (d0 > m + DMAX_THR) {
            float sc = __expf(m - d0);
            l *= sc;
#pragma unroll
            for (int p = 0; p < 8; ++p) acc[p] *= sc;
            m = d0;
        }
        float pw0 = __expf(d0 - m);
        l += pw0;
#pragma unroll
        for (int p = 0; p < 8; ++p)
            acc[p] = fmaf(pw0, (float)e0[p >> 1][p & 1], acc[p]);
    }

    // merge the two halves (same channels & head, disjoint edges)
    float mo = __shfl_xor(m, 32);
    float lo = __shfl_xor(l, 32);
    float M = fmaxf(m, mo);
    float sA = __expf(m - M), sB = __expf(mo - M);
    float lsum = l * sA + lo * sB;
    float inv = 1.f / (lsum + 1e-16f);
    us8 o;
#pragma unroll
    for (int p = 0; p < 8; ++p) {
        float ao = __shfl_xor(acc[p], 32);
        float v = (acc[p] * sA + ao * sB) * inv + bias[ch0 + p];
        o[p] = f2h(fmaxf(v, 0.f));
    }
    if (half == 0)
        *reinterpret_cast<us8*>(out + (size_t)node * 256 + ch0) = o;
}

// ---------------- fused MFMA GEMM (f16) ----------------
template<int KIN, int NOUT>
__global__ __launch_bounds__(256)
void gemm_mfma2(const unsigned short* __restrict__ X,
                const unsigned short* __restrict__ WfL, const float* __restrict__ bL,
                unsigned short* __restrict__ outL,
                const unsigned short* __restrict__ WfR, const float* __restrict__ bR,
                unsigned short* __restrict__ outR) {
    constexpr int KB = KIN / 32, NT = NOUT / 16;
    int lane = threadIdx.x & 63;
    int wv = threadIdx.x >> 6;
    int row0 = blockIdx.x * 64 + wv * 16;
    int r16 = lane & 15, kg = lane >> 4;

    int arow = row0 + r16; if (arow >= NN) arow = NN - 1;
    const unsigned short* xrow = X + (size_t)arow * KIN + kg * 8;
    h8 af[KB];
#pragma unroll
    for (int kb = 0; kb < KB; ++kb)
        af[kb] = *reinterpret_cast<const h8*>(xrow + kb * 32);

    const unsigned short* Wf[2] = { WfL, WfR };
    const float* bb[2] = { bL, bR };
    unsigned short* oo[2] = { outL, outR };

#pragma unroll
    for (int w = 0; w < 2; ++w) {
        const h8* wbase = reinterpret_cast<const h8*>(Wf[w]) + lane;
        const float* bw = bb[w];
        unsigned short* ow = oo[w];
#pragma unroll 1
        for (int t = 0; t < NT; ++t) {
            f32x4 acc = {0.f, 0.f, 0.f, 0.f};
            const h8* wp = wbase + (size_t)t * KB * 64;
#pragma unroll
            for (int kb = 0; kb < KB; ++kb)
                acc = __builtin_amdgcn_mfma_f32_16x16x32_f16(af[kb], wp[kb * 64], acc, 0, 0, 0);
            float bv = bw[t * 16 + r16];
#pragma unroll
            for (int rg = 0; rg < 4; ++rg) {
                int row = row0 + kg * 4 + rg;
                if (row < NN)
                    ow[(size_t)row * NOUT + t * 16 + r16] = f2h(acc[rg] + bv);
            }
        }
    }
}

// ---------------- GATv2 layer 2 (H=2,C=64): half-wave split, f16 packed math ----------------
__global__ __launch_bounds__(256)
void gat2_fused(const unsigned short* __restrict__ xl, const unsigned short* __restrict__ xr,
                const int* __restrict__ rowptr, const int* __restrict__ col,
                const float* __restrict__ att, const float* __restrict__ bias,
                unsigned short* __restrict__ out) {
    constexpr int HC = 128;
    int lane = threadIdx.x & 63;
    int half = lane >> 5;
    int l32 = lane & 31;
    int node = (blockIdx.x * blockDim.x + threadIdx.x) >> 6;
    if (node >= NN) return;
    int ch0 = l32 * 4;   // lanes 0-15: head0, 16-31: head1 (per half)

    const h2 c02 = (h2){(_Float16)0.2f, (_Float16)0.2f};
    h2 a2[2];
#pragma unroll
    for (int p = 0; p < 2; ++p)
        a2[p] = (h2){(_Float16)att[ch0 + 2*p], (_Float16)att[ch0 + 2*p + 1]};
    const h2* xrp = reinterpret_cast<const h2*>(xr + (size_t)node * HC + ch0);
    h2 xr2[2] = { xrp[0], xrp[1] };

    float m = -INFINITY, l = 0.f, acc[4] = {0.f, 0.f, 0.f, 0.f};

    int beg = rowptr[node], end = rowptr[node + 1];
    int n = end - beg;
    int nh = (n + 1) >> 1;
    int idx = beg + (half ? nh : 0);
    int myEnd = half ? end : beg + nh;

    for (; idx + 1 < myEnd; idx += 2) {
        int s0 = col[idx], s1 = col[idx + 1];
        const h2* p0 = reinterpret_cast<const h2*>(xl + (size_t)s0 * HC + ch0);
        const h2* p1 = reinterpret_cast<const h2*>(xl + (size_t)s1 * HC + ch0);
        h2 e0[2] = { p0[0], p0[1] };
        h2 e1[2] = { p1[0], p1[1] };
        float d0 = 0.f, d1 = 0.f;
#pragma unroll
        for (int p = 0; p < 2; ++p) {
            h2 u0 = e0[p] + xr2[p];
            h2 u1 = e1[p] + xr2[p];
            u0 = __builtin_elementwise_max(u0, u0 * c02);
            u1 = __builtin_elementwise_max(u1, u1 * c02);
            d0 = __builtin_amdgcn_fdot2(u0, a2[p], d0, false);
            d1 = __builtin_amdgcn_fdot2(u1, a2[p], d1, false);
        }
#pragma unroll
        for (int off = 8; off >= 1; off >>= 1) {   // 16-lane head group, stays in half
            d0 += __shfl_xor(d0, off);
            d1 += __shfl_xor(d1, off);
        }
        float pmax = fmaxf(d0, d1);
        if (pmax > m + DMAX_THR) {
            float sc = __expf(m - pmax);
            l *= sc;
#pragma unroll
            for (int p = 0; p < 4; ++p) acc[p] *= sc;
            m = pmax;
        }
        float pw0 = __expf(d0 - m), pw1 = __expf(d1 - m);
        l += pw0 + pw1;
#pragma unroll
        for (int p = 0; p < 4; ++p)
            acc[p] = fmaf(pw0, (float)e0[p >> 1][p & 1],
                     fmaf(pw1, (float)e1[p >> 1][p & 1], acc[p]));
    }
    if (idx < myEnd) {
        int s0 = col[idx];
        const h2* p0 = reinterpret_cast<const h2*>(xl + (size_t)s0 * HC + ch0);
        h2 e0[2] = { p0[0], p0[1] };
        float d0 = 0.f;
#pragma unroll
        for (int p = 0; p < 2; ++p) {
            h2 u0 = e0[p] + xr2[p];
            u0 = __builtin_elementwise_max(u0, u0 * c02);
            d0 = __builtin_amdgcn_fdot2(u0, a2[p], d0, false);
        }
#pragma unroll
        for (int off = 8; off >= 1; off >>= 1) d0 += __shfl_xor(d0, off);
        if (d0 > m + DMAX_THR) {
            float sc = __expf(m - d0);
            l *= sc;
#pragma unroll
            for (int p = 0; p < 4; ++p) acc[p] *= sc;
            m = d0;
        }
        float pw0 = __expf(d0 - m);
        l += pw0;
#pragma unroll
        for (int p = 0; p < 4; ++p)
            acc[p] = fmaf(pw0, (float)e0[p >> 1][p & 1], acc[p]);
    }

    // merge halves (same channels/head, disjoint edges)
    float mo = __shfl_xor(m, 32);
    float lo = __shfl_xor(l, 32);
    float M = fmaxf(m, mo);
    float sA = __expf(m - M), sB = __expf(mo - M);
    float lsum = l * sA + lo * sB;
    float inv = 1.f / (lsum + 1e-16f);
    unsigned short o[4];
#pragma unroll
    for (int p = 0; p < 4; ++p) {
        float ao = __shfl_xor(acc[p], 32);
        float v = (acc[p] * sA + ao * sB) * inv + bias[ch0 + p];
        o[p] = f2h(fmaxf(v, 0.f));
    }
    if (half == 0)
        *reinterpret_cast<ushort4*>(out + (size_t)node * HC + ch0) =
            make_ushort4(o[0], o[1], o[2], o[3]);
}

// ---------------- GATv2 layer 3 (H=1,C=256): half-wave split, f16 packed math ----------------
__global__ __launch_bounds__(256)
void gat3_fused(const unsigned short* __restrict__ xl, const unsigned short* __restrict__ xr,
                const int* __restrict__ rowptr, const int* __restrict__ col,
                const float* __restrict__ att, const float* __restrict__ bias,
                float* __restrict__ out) {
    int lane = threadIdx.x & 63;
    int half = lane >> 5;
    int node = (blockIdx.x * blockDim.x + threadIdx.x) >> 6;
    if (node >= NN) return;
    int ch0 = (lane & 31) * 8;

    const h2 c02 = (h2){(_Float16)0.2f, (_Float16)0.2f};
    h2 a2[4];
#pragma unroll
    for (int p = 0; p < 4; ++p)
        a2[p] = (h2){(_Float16)att[ch0 + 2*p], (_Float16)att[ch0 + 2*p + 1]};
    const h2* xrp = reinterpret_cast<const h2*>(xr + (size_t)node * 256 + ch0);
    h2 xr2[4] = { xrp[0], xrp[1], xrp[2], xrp[3] };

    float m = -INFINITY, l = 0.f, acc[8];
#pragma unroll
    for (int p = 0; p < 8; ++p) acc[p] = 0.f;

    int beg = rowptr[node], end = rowptr[node + 1];
    int n = end - beg;
    int nh = (n + 1) >> 1;
    int idx = beg + (half ? nh : 0);
    int myEnd = half ? end : beg + nh;

    for (; idx + 1 < myEnd; idx += 2) {
        int s0 = col[idx], s1 = col[idx + 1];
        const h2* p0 = reinterpret_cast<const h2*>(xl + (size_t)s0 * 256 + ch0);
        const h2* p1 = reinterpret_cast<const h2*>(xl + (size_t)s1 * 256 + ch0);
        h2 e0[4] = { p0[0], p0[1], p0[2], p0[3] };
        h2 e1[4] = { p1[0], p1[1], p1[2], p1[3] };
        float d0 = 0.f, d1 = 0.f;
#pragma unroll
        for (int p = 0; p < 4; ++p) {
            h2 u0 = e0[p] + xr2[p];
            h2 u1 = e1[p] + xr2[p];
            u0 = __builtin_elementwise_max(u0, u0 * c02);
            u1 = __builtin_elementwise_max(u1, u1 * c02);
            d0 = __builtin_amdgcn_fdot2(u0, a2[p], d0, false);
            d1 = __builtin_amdgcn_fdot2(u1, a2[p], d1, false);
        }
#pragma unroll
        for (int off = 16; off >= 1; off >>= 1) {   // stays within 32-lane half
            d0 += __shfl_xor(d0, off);
            d1 += __shfl_xor(d1, off);
        }
        float pmax = fmaxf(d0, d1);
        if (pmax > m + DMAX_THR) {
            float sc = __expf(m - pmax);
            l *= sc;
#pragma unroll
            for (int p = 0; p < 8; ++p) acc[p] *= sc;
            m = pmax;
        }
        float pw0 = __expf(d0 - m), pw1 = __expf(d1 - m);
        l += pw0 + pw1;
#pragma unroll
        for (int p = 0; p < 8; ++p)
            acc[p] = fmaf(pw0, (float)e0[p >> 1][p & 1],
                     fmaf(pw1, (float)e1[p >> 1][p & 1], acc[p]));
    }
    if (idx < myEnd) {
        int s0 = col[idx];
        const h2* p0 = reinterpret_cast<const h2*>(xl + (size_t)s0 * 256 + ch0);
        h2 e0[4] = { p0[0], p0[1], p0[2], p0[3] };
        float d0 = 0.f;
#pragma unroll
        for (int p = 0; p < 4; ++p) {
            h2 u0 = e0[p] + xr2[p];
            u0 = __builtin_elementwise_max(u0, u0 * c02);
            d0 = __builtin_amdgcn_fdot2(u0, a2[p], d0, false);
        }
#pragma unroll
        for (int off = 16; off >= 1; off >>= 1) d0 += __shfl_xor(d0, off);
        if (d0 > m + DMAX_THR) {
            float sc = __expf(m - d0);
            l *= sc;
#pragma unroll
            for (int p = 0; p < 8; ++p) acc[p] *= sc;
            m = d0;
        }
        float pw0 = __expf(d0 - m);
        l += pw0;
#pragma unroll
        for (int p = 0; p < 8; ++p)
            acc[p] = fmaf(pw0, (float)e0[p >> 1][p & 1], acc[p]);
    }

    // merge the two halves
    float mo = __shfl_xor(m, 32);
    float lo = __shfl_xor(l, 32);
    float M = fmaxf(m, mo);
    float sA = __expf(m - M), sB = __expf(mo - M);
    float lsum = l * sA + lo * sB;
    float inv = 1.f / (lsum + 1e-16f);
    float o[8];
#pragma unroll
    for (int p = 0; p < 8; ++p) {
        float ao = __shfl_xor(acc[p], 32);
        o[p] = (acc[p] * sA + ao * sB) * inv + bias[ch0 + p];
    }
    if (half == 0) {
        *reinterpret_cast<float4*>(out + (size_t)node * 256 + ch0) =
            make_float4(o[0], o[1], o[2], o[3]);
        *reinterpret_cast<float4*>(out + (size_t)node * 256 + ch0 + 4) =
            make_float4(o[4], o[5], o[6], o[7]);
    }
}

// ---------------- pool + head MLP ----------------
__global__ __launch_bounds__(256)
void graph_bounds(const int* __restrict__ batch, float* __restrict__ cnt,
                  float* __restrict__ pooled) {
    int g = blockIdx.x, tid = threadIdx.x;
    pooled[g * 256 + tid] = 0.f;
    if (tid == 0) {
        int lo = 0, hi = NN;
        while (lo < hi) { int mid = (lo + hi) >> 1; if (batch[mid] < g) lo = mid + 1; else hi = mid; }
        int lo2 = lo, hi2 = NN;
        while (lo2 < hi2) { int mid = (lo2 + hi2) >> 1; if (batch[mid] < g + 1) lo2 = mid + 1; else hi2 = mid; }
        cnt[g] = (float)(lo2 - lo);
    }
}

__global__ __launch_bounds__(256)
void pool_sum(const float* __restrict__ h, const int* __restrict__ batch,
              float* pooled) {
    __shared__ int gb[32];
    int c = threadIdx.x;
    int n0 = blockIdx.x * 32;
    int n1 = min(n0 + 32, NN);
    int cnt = n1 - n0;
    if (c < cnt) gb[c] = batch[n0 + c];
    __syncthreads();
    if (gb[0] == gb[cnt - 1]) {
        float acc = 0.f;
#pragma unroll 4
        for (int i = 0; i < cnt; ++i) acc += h[(size_t)(n0 + i) * 256 + c];
        atomicAdd(&pooled[gb[0] * 256 + c], acc);
    } else {
        int cur = gb[0]; float acc = 0.f;
        for (int i = 0; i < cnt; ++i) {
            int g = gb[i];
            if (g != cur) { atomicAdd(&pooled[cur * 256 + c], acc); acc = 0.f; cur = g; }
            acc += h[(size_t)(n0 + i) * 256 + c];
        }
        atomicAdd(&pooled[cur * 256 + c], acc);
    }
}

__global__ __launch_bounds__(256)
void mlp_ln(const float* __restrict__ pooled, const float* __restrict__ cnt,
            const float* __restrict__ We1, const float* __restrict__ be1,
            const float* __restrict__ We2, const float* __restrict__ be2,
            const float* __restrict__ lng, const float* __restrict__ lnb,
            float* __restrict__ out) {
    __shared__ float p[256];
    __shared__ float t[512];
    __shared__ float red[8];
    int g = blockIdx.x, tid = threadIdx.x;
    p[tid] = pooled[g * 256 + tid] / fmaxf(cnt[g], 1.0f);
    __syncthreads();
    for (int jj = tid; jj < 512; jj += 256) {
        float s = be1[jj];
        for (int k = 0; k < 256; ++k) s = fmaf(p[k], We1[(size_t)k * 512 + jj], s);
        t[jj] = fmaxf(s, 0.f);
    }
    __syncthreads();
    float z = be2[tid];
    for (int k = 0; k < 512; ++k) z = fmaf(t[k], We2[(size_t)k * 256 + tid], z);
    float sv = z, sq = z * z;
#pragma unroll
    for (int off = 32; off >= 1; off >>= 1) {
        sv += __shfl_xor(sv, off);
        sq += __shfl_xor(sq, off);
    }
    int wv = tid >> 6;
    if ((tid & 63) == 0) { red[wv] = sv; red[4 + wv] = sq; }
    __syncthreads();
    float tot = red[0] + red[1] + red[2] + red[3];
    float totq = red[4] + red[5] + red[6] + red[7];
    float mu = tot * (1.f / 256.f);
    float var = totq * (1.f / 256.f) - mu * mu;
    float r = rsqrtf(var + 1e-5f);
    out[g * 256 + tid] = (z - mu) * r * lng[tid] + lnb[tid];
}

extern "C" void kernel_launch(void* const* d_in, const int* in_sizes, int n_in,
                              void* d_out, int out_size, void* d_ws, size_t ws_size,
                              hipStream_t stream) {
    const float* x   = (const float*)d_in[0];
    const int*   ei  = (const int*)d_in[1];
    const int*   bat = (const int*)d_in[2];
    const float *W1l = (const float*)d_in[3], *b1l = (const float*)d_in[4];
    const float *W1r = (const float*)d_in[5], *b1r = (const float*)d_in[6];
    const float *a1  = (const float*)d_in[7], *c1b = (const float*)d_in[8];
    const float *W2l = (const float*)d_in[9],  *b2l = (const float*)d_in[10];
    const float *W2r = (const float*)d_in[11], *b2r = (const float*)d_in[12];
    const float *a2  = (const float*)d_in[13], *c2b = (const float*)d_in[14];
    const float *W3l = (const float*)d_in[15], *b3l = (const float*)d_in[16];
    const float *W3r = (const float*)d_in[17], *b3r = (const float*)d_in[18];
    const float *a3  = (const float*)d_in[19], *c3b = (const float*)d_in[20];
    const float *We1 = (const float*)d_in[21], *be1 = (const float*)d_in[22];
    const float *We2 = (const float*)d_in[23], *be2 = (const float*)d_in[24];
    const float *lng = (const float*)d_in[25], *lnb = (const float*)d_in[26];

    char* base = (char*)d_ws;
    size_t off = 0;
    auto nxt = [&](size_t bytes) { char* p = base + off; off = (off + bytes + 255) & ~(size_t)255; return p; };
    unsigned short* Abuf = (unsigned short*)nxt((size_t)NN * 256 * 2);
    unsigned short* Bbuf = (unsigned short*)nxt((size_t)NN * 256 * 2);
    unsigned short* Hb16 = (unsigned short*)nxt((size_t)NN * 256 * 2);
    float* Hb32 = (float*)nxt((size_t)NN * 256 * 4);
    unsigned short* Qtab = (unsigned short*)nxt((size_t)NN * 256 * 2);
    unsigned short* Rtab = (unsigned short*)nxt((size_t)NN * 256 * 2);
    int* deg    = (int*)nxt(NN * 4);
    int* rowptr = (int*)nxt((NN + 1) * 4);
    int* cursor = (int*)nxt(NN * 4);
    int* colv   = (int*)nxt((size_t)ETOT * 4);
    int* psum   = (int*)nxt(1024 * 4);
    float* POOL = (float*)nxt(NG * 256 * 4);
    float* CNT  = (float*)nxt(NG * 4);
    unsigned short* Wf2l = (unsigned short*)nxt(256 * 128 * 2);
    unsigned short* Wf2r = (unsigned short*)nxt(256 * 128 * 2);
    unsigned short* Wf3l = (unsigned short*)nxt(128 * 256 * 2);
    unsigned short* Wf3r = (unsigned short*)nxt(128 * 256 * 2);

    const int GEMM_BLKS = (NN + 63) / 64;
    const int NB_NODE = (NN + 3) / 4;   // wave-per-node, 4 waves/block

    // ---- CSR build ----
    hipMemsetAsync(deg, 0, NN * sizeof(int), stream);
    hist_dst<<<(ETOT + 255) / 256, 256, 0, stream>>>(ei, deg);
    scan1<<<SCAN_BLKS, 64, 0, stream>>>(deg, psum);
    scan2<<<1, 1024, 0, stream>>>(psum);
    scan3<<<SCAN_BLKS, 64, 0, stream>>>(deg, psum, rowptr, cursor);
    scatter_csr<<<(ETOT + 255) / 256, 256, 0, stream>>>(ei, cursor, colv);

    // ---- weight pre-pack + Q/R tables ----
    wfrag_all<<<(4 * 32768) / 256, 256, 0, stream>>>(W2l, W2r, W3l, W3r, Wf2l, Wf2r, Wf3l, Wf3r);
    {
        dim3 g(4, (NN + 31) / 32);
        qr_prep<<<g, 256, 0, stream>>>(x, W1l, b1l, W1r, b1r, Qtab, Rtab);
    }

    // ---- Layer 1: table-based GAT (H=4,C=64) ----
    gat1_fused<<<NB_NODE, 256, 0, stream>>>(Qtab, Rtab, rowptr, colv, a1, c1b, Hb16);

    // ---- Layer 2: 256 -> (H=2,C=64) ----
    gemm_mfma2<256, 128><<<GEMM_BLKS, 256, 0, stream>>>(Hb16, Wf2l, b2l, Abuf, Wf2r, b2r, Bbuf);
    gat2_fused<<<NB_NODE, 256, 0, stream>>>(Abuf, Bbuf, rowptr, colv, a2, c2b, Hb16);

    // ---- Layer 3: 128 -> (H=1,C=256), concat=False ----
    gemm_mfma2<128, 256><<<GEMM_BLKS, 256, 0, stream>>>(Hb16, Wf3l, b3l, Abuf, Wf3r, b3r, Bbuf);
    gat3_fused<<<NB_NODE, 256, 0, stream>>>(Abuf, Bbuf, rowptr, colv, a3, c3b, Hb32);

    // ---- pool + MLP + LN ----
    graph_bounds<<<NG, 256, 0, stream>>>(bat, CNT, POOL);
    pool_sum<<<(NN + 31) / 32, 256, 0, stream>>>(Hb32, bat, POOL);
    mlp_ln<<<NG, 256, 0, stream>>>(POOL, CNT, We1, be1, We2, be2, lng, lnb, (float*)d_out);
}

// Round 14
// 413.360 us; speedup vs baseline: 1.1934x; 1.0080x over previous
//
#include <hip/hip_runtime.h>
#include <hip/hip_bf16.h>
#include <math.h>

#define NN 50000
#define NE0 800000
#define ETOT (NE0 + NN)
#define NG 64
#define SCAN_BLKS ((NN + 63) / 64)   // 782
#define DMAX_THR 8.0f                // defer-max threshold (exp headroom e^8)

typedef _Float16 h2 __attribute__((ext_vector_type(2)));
typedef _Float16 h8 __attribute__((ext_vector_type(8)));
typedef float    f32x4 __attribute__((ext_vector_type(4)));
typedef unsigned short us8 __attribute__((ext_vector_type(8)));

__device__ __forceinline__ unsigned short f2h(float f) {
    _Float16 h = (_Float16)f;
    return __builtin_bit_cast(unsigned short, h);
}
__device__ __forceinline__ float h2f(unsigned short u) {
    return (float)__builtin_bit_cast(_Float16, u);
}

__device__ __forceinline__ void edge_sd(const int* __restrict__ ei, int e, int& s, int& d) {
    if (e < NE0) { s = ei[e]; d = ei[NE0 + e]; }
    else { s = e - NE0; d = s; }
}

// ---------------- CSR build (by dst) ----------------
__global__ __launch_bounds__(256)
void hist_dst(const int* __restrict__ ei, int* __restrict__ deg) {
    int e = blockIdx.x * blockDim.x + threadIdx.x;
    if (e >= ETOT) return;
    int s, d; edge_sd(ei, e, s, d); (void)s;
    atomicAdd(&deg[d], 1);
}

__global__ __launch_bounds__(64)
void scan1(const int* __restrict__ deg, int* __restrict__ psum) {
    int i = blockIdx.x * 64 + threadIdx.x;
    int v = (i < NN) ? deg[i] : 0;
#pragma unroll
    for (int off = 1; off < 64; off <<= 1) {
        int t = __shfl_up(v, off);
        if ((int)threadIdx.x >= off) v += t;
    }
    if (threadIdx.x == 63) psum[blockIdx.x] = v;
}

__global__ __launch_bounds__(1024)
void scan2(int* __restrict__ psum) {
    __shared__ int sm[1024];
    int t = threadIdx.x;
    sm[t] = (t < SCAN_BLKS) ? psum[t] : 0;
    __syncthreads();
    for (int off = 1; off < 1024; off <<= 1) {
        int v = (t >= off) ? sm[t - off] : 0;
        __syncthreads();
        sm[t] += v;
        __syncthreads();
    }
    if (t < SCAN_BLKS) psum[t] = (t == 0) ? 0 : sm[t - 1];
}

__global__ __launch_bounds__(64)
void scan3(const int* __restrict__ deg, const int* __restrict__ psum,
           int* __restrict__ rowptr, int* __restrict__ cursor) {
    int i = blockIdx.x * 64 + threadIdx.x;
    int v = (i < NN) ? deg[i] : 0;
    int inc = v;
#pragma unroll
    for (int off = 1; off < 64; off <<= 1) {
        int t = __shfl_up(inc, off);
        if ((int)threadIdx.x >= off) inc += t;
    }
    int excl = inc - v + psum[blockIdx.x];
    if (i < NN) { rowptr[i] = excl; cursor[i] = excl; }
    if (i == NN - 1) rowptr[NN] = excl + v;   // == ETOT
}

__global__ __launch_bounds__(256)
void scatter_csr(const int* __restrict__ ei, int* __restrict__ cursor,
                 int* __restrict__ col) {
    int e = blockIdx.x * blockDim.x + threadIdx.x;
    if (e >= ETOT) return;
    int s, d; edge_sd(ei, e, s, d);
    int pos = atomicAdd(&cursor[d], 1);
    col[pos] = s;
}

// ---------------- weight pre-pack (all 4 matrices) + deg zero ----------------
__device__ __forceinline__ void wfrag_one(const float* W, unsigned short* Wf,
                                          int r, int KB, int NOUT) {
    int j = r & 7;
    int l = (r >> 3) & 63;
    int rest = r >> 9;
    int kb = rest % KB, t = rest / KB;
    int k = kb * 32 + (l >> 4) * 8 + j;
    int colj = t * 16 + (l & 15);
    Wf[r] = f2h(W[(size_t)k * NOUT + colj]);
}
__global__ __launch_bounds__(256)
void wfrag_all(const float* __restrict__ W2l, const float* __restrict__ W2r,
               const float* __restrict__ W3l, const float* __restrict__ W3r,
               unsigned short* __restrict__ Wf2l, unsigned short* __restrict__ Wf2r,
               unsigned short* __restrict__ Wf3l, unsigned short* __restrict__ Wf3r,
               int* __restrict__ deg) {
    int tid = blockIdx.x * 256 + threadIdx.x;   // [0, 4*32768)
    if (tid < NN) deg[tid] = 0;                 // fold memset
    int seg = tid >> 15;
    int r = tid & 32767;
    if (seg == 0)      wfrag_one(W2l, Wf2l, r, 8, 128);
    else if (seg == 1) wfrag_one(W2r, Wf2r, r, 8, 128);
    else if (seg == 2) wfrag_one(W3l, Wf3l, r, 4, 256);
    else               wfrag_one(W3r, Wf3r, r, 4, 256);
}

// ---------------- Q/R tables: Q = x@W1l + b1l, R = x@W1r + b1r (f16) ----------------
__global__ __launch_bounds__(256)
void qr_prep(const float* __restrict__ X,
             const float* __restrict__ W1l, const float* __restrict__ b1l,
             const float* __restrict__ W1r, const float* __restrict__ b1r,
             unsigned short* __restrict__ Q, unsigned short* __restrict__ R) {
    int j = blockIdx.x * 64 + (threadIdx.x & 63);
    int row0 = (blockIdx.y * 4 + (threadIdx.x >> 6)) * 8;
    float l0 = W1l[j], l1 = W1l[256 + j], l2 = W1l[512 + j], l3 = W1l[768 + j];
    float r0 = W1r[j], r1 = W1r[256 + j], r2 = W1r[512 + j], r3 = W1r[768 + j];
    float bl = b1l[j], br = b1r[j];
#pragma unroll
    for (int r = 0; r < 8; ++r) {
        int row = row0 + r;
        if (row >= NN) break;
        float4 xv = *reinterpret_cast<const float4*>(X + (size_t)row * 4);
        float q = fmaf(xv.x, l0, fmaf(xv.y, l1, fmaf(xv.z, l2, fmaf(xv.w, l3, bl))));
        float rr = fmaf(xv.x, r0, fmaf(xv.y, r1, fmaf(xv.z, r2, fmaf(xv.w, r3, br))));
        Q[(size_t)row * 256 + j] = f2h(q);
        R[(size_t)row * 256 + j] = f2h(rr);
    }
}

// ---------------- unified GATv2 aggregation ----------------
// Half-wave split: lanes 0-31 / 32-63 run independent online softmaxes over
// disjoint halves of the node's edge list; merged at end via shfl_xor(.,32).
// CPL channels/lane (HC = 32*CPL), REDW lanes per head group.
// 4-edge inner batches; branchy defer-max; f16 packed dot (fdot2).
template<int CPL, int REDW, bool RELU>
__global__ __launch_bounds__(256)
void gat_fused(const unsigned short* __restrict__ xl, const unsigned short* __restrict__ xr,
               const int* __restrict__ rowptr, const int* __restrict__ col,
               const float* __restrict__ att, const float* __restrict__ bias,
               unsigned short* __restrict__ out) {
    constexpr int HC = CPL * 32;
    constexpr int NP = CPL / 2;
    int lane = threadIdx.x & 63;
    int half = lane >> 5;
    int node = (blockIdx.x * blockDim.x + threadIdx.x) >> 6;
    if (node >= NN) return;
    int ch0 = (lane & 31) * CPL;

    const h2 c02 = (h2){(_Float16)0.2f, (_Float16)0.2f};
    h2 a2[NP];
#pragma unroll
    for (int p = 0; p < NP; ++p)
        a2[p] = (h2){(_Float16)att[ch0 + 2*p], (_Float16)att[ch0 + 2*p + 1]};
    h2 r2[NP];
    {
        const h2* rp = reinterpret_cast<const h2*>(xr + (size_t)node * HC + ch0);
#pragma unroll
        for (int p = 0; p < NP; ++p) r2[p] = rp[p];
    }

    float m = -INFINITY, l = 0.f, acc[CPL];
#pragma unroll
    for (int p = 0; p < CPL; ++p) acc[p] = 0.f;

    int beg = rowptr[node], end = rowptr[node + 1];
    int n = end - beg;
    int nh = (n + 1) >> 1;
    int idx = beg + (half ? nh : 0);
    int myEnd = half ? end : beg + nh;

    for (; idx + 3 < myEnd; idx += 4) {
        int s[4] = { col[idx], col[idx + 1], col[idx + 2], col[idx + 3] };
        h2 e[4][NP];
#pragma unroll
        for (int q = 0; q < 4; ++q) {
            const h2* pq = reinterpret_cast<const h2*>(xl + (size_t)s[q] * HC + ch0);
#pragma unroll
            for (int p = 0; p < NP; ++p) e[q][p] = pq[p];
        }
        float d[4] = { 0.f, 0.f, 0.f, 0.f };
#pragma unroll
        for (int p = 0; p < NP; ++p) {
#pragma unroll
            for (int q = 0; q < 4; ++q) {
                h2 u = e[q][p] + r2[p];
                u = __builtin_elementwise_max(u, u * c02);
                d[q] = __builtin_amdgcn_fdot2(u, a2[p], d[q], false);
            }
        }
#pragma unroll
        for (int off = REDW >> 1; off >= 1; off >>= 1) {
#pragma unroll
            for (int q = 0; q < 4; ++q) d[q] += __shfl_xor(d[q], off);
        }
        float pmax = fmaxf(fmaxf(d[0], d[1]), fmaxf(d[2], d[3]));
        if (pmax > m + DMAX_THR) {           // rare path (per head group)
            float sc = __expf(m - pmax);
            l *= sc;
#pragma unroll
            for (int p = 0; p < CPL; ++p) acc[p] *= sc;
            m = pmax;
        }
        float pw[4];
#pragma unroll
        for (int q = 0; q < 4; ++q) pw[q] = __expf(d[q] - m);
        l += (pw[0] + pw[1]) + (pw[2] + pw[3]);
#pragma unroll
        for (int p = 0; p < CPL; ++p) {
            float t0 = fmaf(pw[0], (float)e[0][p >> 1][p & 1],
                            pw[1] * (float)e[1][p >> 1][p & 1]);
            float t1 = fmaf(pw[2], (float)e[2][p >> 1][p & 1],
                            pw[3] * (float)e[3][p >> 1][p & 1]);
            acc[p] += t0 + t1;
        }
    }
    for (; idx < myEnd; ++idx) {
        int s0 = col[idx];
        const h2* p0 = reinterpret_cast<const h2*>(xl + (size_t)s0 * HC + ch0);
        h2 e0[NP];
#pragma unroll
        for (int p = 0; p < NP; ++p) e0[p] = p0[p];
        float d0 = 0.f;
#pragma unroll
        for (int p = 0; p < NP; ++p) {
            h2 u0 = e0[p] + r2[p];
            u0 = __builtin_elementwise_max(u0, u0 * c02);
            d0 = __builtin_amdgcn_fdot2(u0, a2[p], d0, false);
        }
#pragma unroll
        for (int off = REDW >> 1; off >= 1; off >>= 1) d0 += __shfl_xor(d0, off);
        if (d0 > m + DMAX_THR) {
            float sc = __expf(m - d0);
            l *= sc;
#pragma unroll
            for (int p = 0; p < CPL; ++p) acc[p] *= sc;
            m = d0;
        }
        float pw0 = __expf(d0 - m);
        l += pw0;
#pragma unroll
        for (int p = 0; p < CPL; ++p)
            acc[p] = fmaf(pw0, (float)e0[p >> 1][p & 1], acc[p]);
    }

    // merge the two halves (same channels & head, disjoint edges)
    float mo = __shfl_xor(m, 32);
    float lo = __shfl_xor(l, 32);
    float M = fmaxf(m, mo);
    float sA = __expf(m - M), sB = __expf(mo - M);
    float lsum = l * sA + lo * sB;
    float inv = 1.f / (lsum + 1e-16f);
    unsigned short o[CPL];
#pragma unroll
    for (int p = 0; p < CPL; ++p) {
        float ao = __shfl_xor(acc[p], 32);
        float v = (acc[p] * sA + ao * sB) * inv + bias[ch0 + p];
        if (RELU) v = fmaxf(v, 0.f);
        o[p] = f2h(v);
    }
    if (half == 0) {
        if constexpr (CPL == 8) {
            us8 ov;
#pragma unroll
            for (int p = 0; p < 8; ++p) ov[p] = o[p];
            *reinterpret_cast<us8*>(out + (size_t)node * HC + ch0) = ov;
        } else {
            *reinterpret_cast<ushort4*>(out + (size_t)node * HC + ch0) =
                make_ushort4(o[0], o[1], o[2], o[3]);
        }
    }
}

// ---------------- fused MFMA GEMM (f16) ----------------
template<int KIN, int NOUT>
__global__ __launch_bounds__(256)
void gemm_mfma2(const unsigned short* __restrict__ X,
                const unsigned short* __restrict__ WfL, const float* __restrict__ bL,
                unsigned short* __restrict__ outL,
                const unsigned short* __restrict__ WfR, const float* __restrict__ bR,
                unsigned short* __restrict__ outR) {
    constexpr int KB = KIN / 32, NT = NOUT / 16;
    int lane = threadIdx.x & 63;
    int wv = threadIdx.x >> 6;
    int row0 = blockIdx.x * 64 + wv * 16;
    int r16 = lane & 15, kg = lane >> 4;

    int arow = row0 + r16; if (arow >= NN) arow = NN - 1;
    const unsigned short* xrow = X + (size_t)arow * KIN + kg * 8;
    h8 af[KB];
#pragma unroll
    for (int kb = 0; kb < KB; ++kb)
        af[kb] = *reinterpret_cast<const h8*>(xrow + kb * 32);

    const unsigned short* Wf[2] = { WfL, WfR };
    const float* bb[2] = { bL, bR };
    unsigned short* oo[2] = { outL, outR };

#pragma unroll
    for (int w = 0; w < 2; ++w) {
        const h8* wbase = reinterpret_cast<const h8*>(Wf[w]) + lane;
        const float* bw = bb[w];
        unsigned short* ow = oo[w];
#pragma unroll 1
        for (int t = 0; t < NT; ++t) {
            f32x4 acc = {0.f, 0.f, 0.f, 0.f};
            const h8* wp = wbase + (size_t)t * KB * 64;
#pragma unroll
            for (int kb = 0; kb < KB; ++kb)
                acc = __builtin_amdgcn_mfma_f32_16x16x32_f16(af[kb], wp[kb * 64], acc, 0, 0, 0);
            float bv = bw[t * 16 + r16];
#pragma unroll
            for (int rg = 0; rg < 4; ++rg) {
                int row = row0 + kg * 4 + rg;
                if (row < NN)
                    ow[(size_t)row * NOUT + t * 16 + r16] = f2h(acc[rg] + bv);
            }
        }
    }
}

// ---------------- pool + head MLP ----------------
__global__ __launch_bounds__(256)
void graph_bounds(const int* __restrict__ batch, float* __restrict__ cnt,
                  float* __restrict__ pooled) {
    int g = blockIdx.x, tid = threadIdx.x;
    pooled[g * 256 + tid] = 0.f;
    if (tid == 0) {
        int lo = 0, hi = NN;
        while (lo < hi) { int mid = (lo + hi) >> 1; if (batch[mid] < g) lo = mid + 1; else hi = mid; }
        int lo2 = lo, hi2 = NN;
        while (lo2 < hi2) { int mid = (lo2 + hi2) >> 1; if (batch[mid] < g + 1) lo2 = mid + 1; else hi2 = mid; }
        cnt[g] = (float)(lo2 - lo);
    }
}

__global__ __launch_bounds__(256)
void pool_sum(const unsigned short* __restrict__ h, const int* __restrict__ batch,
              float* pooled) {
    __shared__ int gb[32];
    int c = threadIdx.x;
    int n0 = blockIdx.x * 32;
    int n1 = min(n0 + 32, NN);
    int cnt = n1 - n0;
    if (c < cnt) gb[c] = batch[n0 + c];
    __syncthreads();
    if (gb[0] == gb[cnt - 1]) {
        float acc = 0.f;
#pragma unroll 4
        for (int i = 0; i < cnt; ++i) acc += h2f(h[(size_t)(n0 + i) * 256 + c]);
        atomicAdd(&pooled[gb[0] * 256 + c], acc);
    } else {
        int cur = gb[0]; float acc = 0.f;
        for (int i = 0; i < cnt; ++i) {
            int g = gb[i];
            if (g != cur) { atomicAdd(&pooled[cur * 256 + c], acc); acc = 0.f; cur = g; }
            acc += h2f(h[(size_t)(n0 + i) * 256 + c]);
        }
        atomicAdd(&pooled[cur * 256 + c], acc);
    }
}

__global__ __launch_bounds__(256)
void mlp_ln(const float* __restrict__ pooled, const float* __restrict__ cnt,
            const float* __restrict__ We1, const float* __restrict__ be1,
            const float* __restrict__ We2, const float* __restrict__ be2,
            const float* __restrict__ lng, const float* __restrict__ lnb,
            float* __restrict__ out) {
    __shared__ float p[256];
    __shared__ float t[512];
    __shared__ float red[8];
    int g = blockIdx.x, tid = threadIdx.x;
    p[tid] = pooled[g * 256 + tid] / fmaxf(cnt[g], 1.0f);
    __syncthreads();
    for (int jj = tid; jj < 512; jj += 256) {
        float s = be1[jj];
        for (int k = 0; k < 256; ++k) s = fmaf(p[k], We1[(size_t)k * 512 + jj], s);
        t[jj] = fmaxf(s, 0.f);
    }
    __syncthreads();
    float z = be2[tid];
    for (int k = 0; k < 512; ++k) z = fmaf(t[k], We2[(size_t)k * 256 + tid], z);
    float sv = z, sq = z * z;
#pragma unroll
    for (int off = 32; off >= 1; off >>= 1) {
        sv += __shfl_xor(sv, off);
        sq += __shfl_xor(sq, off);
    }
    int wv = tid >> 6;
    if ((tid & 63) == 0) { red[wv] = sv; red[4 + wv] = sq; }
    __syncthreads();
    float tot = red[0] + red[1] + red[2] + red[3];
    float totq = red[4] + red[5] + red[6] + red[7];
    float mu = tot * (1.f / 256.f);
    float var = totq * (1.f / 256.f) - mu * mu;
    float r = rsqrtf(var + 1e-5f);
    out[g * 256 + tid] = (z - mu) * r * lng[tid] + lnb[tid];
}

extern "C" void kernel_launch(void* const* d_in, const int* in_sizes, int n_in,
                              void* d_out, int out_size, void* d_ws, size_t ws_size,
                              hipStream_t stream) {
    const float* x   = (const float*)d_in[0];
    const int*   ei  = (const int*)d_in[1];
    const int*   bat = (const int*)d_in[2];
    const float *W1l = (const float*)d_in[3], *b1l = (const float*)d_in[4];
    const float *W1r = (const float*)d_in[5], *b1r = (const float*)d_in[6];
    const float *a1  = (const float*)d_in[7], *c1b = (const float*)d_in[8];
    const float *W2l = (const float*)d_in[9],  *b2l = (const float*)d_in[10];
    const float *W2r = (const float*)d_in[11], *b2r = (const float*)d_in[12];
    const float *a2  = (const float*)d_in[13], *c2b = (const float*)d_in[14];
    const float *W3l = (const float*)d_in[15], *b3l = (const float*)d_in[16];
    const float *W3r = (const float*)d_in[17], *b3r = (const float*)d_in[18];
    const float *a3  = (const float*)d_in[19], *c3b = (const float*)d_in[20];
    const float *We1 = (const float*)d_in[21], *be1 = (const float*)d_in[22];
    const float *We2 = (const float*)d_in[23], *be2 = (const float*)d_in[24];
    const float *lng = (const float*)d_in[25], *lnb = (const float*)d_in[26];

    char* base = (char*)d_ws;
    size_t off = 0;
    auto nxt = [&](size_t bytes) { char* p = base + off; off = (off + bytes + 255) & ~(size_t)255; return p; };
    unsigned short* Abuf = (unsigned short*)nxt((size_t)NN * 256 * 2);
    unsigned short* Bbuf = (unsigned short*)nxt((size_t)NN * 256 * 2);
    unsigned short* Hb16 = (unsigned short*)nxt((size_t)NN * 256 * 2);
    unsigned short* Qtab = (unsigned short*)nxt((size_t)NN * 256 * 2);
    unsigned short* Rtab = (unsigned short*)nxt((size_t)NN * 256 * 2);
    int* deg    = (int*)nxt(NN * 4);
    int* rowptr = (int*)nxt((NN + 1) * 4);
    int* cursor = (int*)nxt(NN * 4);
    int* colv   = (int*)nxt((size_t)ETOT * 4);
    int* psum   = (int*)nxt(1024 * 4);
    float* POOL = (float*)nxt(NG * 256 * 4);
    float* CNT  = (float*)nxt(NG * 4);
    unsigned short* Wf2l = (unsigned short*)nxt(256 * 128 * 2);
    unsigned short* Wf2r = (unsigned short*)nxt(256 * 128 * 2);
    unsigned short* Wf3l = (unsigned short*)nxt(128 * 256 * 2);
    unsigned short* Wf3r = (unsigned short*)nxt(128 * 256 * 2);

    const int GEMM_BLKS = (NN + 63) / 64;
    const int NB_NODE = (NN + 3) / 4;   // wave-per-node, 4 waves/block

    // ---- weight pre-pack (also zeroes deg) ----
    wfrag_all<<<(4 * 32768) / 256, 256, 0, stream>>>(W2l, W2r, W3l, W3r,
                                                     Wf2l, Wf2r, Wf3l, Wf3r, deg);
    // ---- CSR build ----
    hist_dst<<<(ETOT + 255) / 256, 256, 0, stream>>>(ei, deg);
    scan1<<<SCAN_BLKS, 64, 0, stream>>>(deg, psum);
    scan2<<<1, 1024, 0, stream>>>(psum);
    scan3<<<SCAN_BLKS, 64, 0, stream>>>(deg, psum, rowptr, cursor);
    scatter_csr<<<(ETOT + 255) / 256, 256, 0, stream>>>(ei, cursor, colv);

    // ---- Q/R tables ----
    {
        dim3 g(4, (NN + 31) / 32);
        qr_prep<<<g, 256, 0, stream>>>(x, W1l, b1l, W1r, b1r, Qtab, Rtab);
    }

    // ---- Layer 1: table-based GAT (H=4,C=64): CPL=8, head=8 lanes ----
    gat_fused<8, 8, true><<<NB_NODE, 256, 0, stream>>>(Qtab, Rtab, rowptr, colv, a1, c1b, Hb16);

    // ---- Layer 2: 256 -> (H=2,C=64): CPL=4, head=16 lanes ----
    gemm_mfma2<256, 128><<<GEMM_BLKS, 256, 0, stream>>>(Hb16, Wf2l, b2l, Abuf, Wf2r, b2r, Bbuf);
    gat_fused<4, 16, true><<<NB_NODE, 256, 0, stream>>>(Abuf, Bbuf, rowptr, colv, a2, c2b, Hb16);

    // ---- Layer 3: 128 -> (H=1,C=256): CPL=8, head=32 lanes ----
    gemm_mfma2<128, 256><<<GEMM_BLKS, 256, 0, stream>>>(Hb16, Wf3l, b3l, Abuf, Wf3r, b3r, Bbuf);
    gat_fused<8, 32, false><<<NB_NODE, 256, 0, stream>>>(Abuf, Bbuf, rowptr, colv, a3, c3b, Hb16);

    // ---- pool + MLP + LN ----
    graph_bounds<<<NG, 256, 0, stream>>>(bat, CNT, POOL);
    pool_sum<<<(NN + 31) / 32, 256, 0, stream>>>(Hb16, bat, POOL);
    mlp_ln<<<NG, 256, 0, stream>>>(POOL, CNT, We1, be1, We2, be2, lng, lnb, (float*)d_out);
}

// Round 15
// 412.110 us; speedup vs baseline: 1.1970x; 1.0030x over previous
//
#include <hip/hip_runtime.h>
#include <hip/hip_bf16.h>
#include <math.h>

#define NN 50000
#define NE0 800000
#define ETOT (NE0 + NN)
#define NG 64
#define SCAN_BLKS ((NN + 63) / 64)   // 782
#define DMAX_THR 4.0f                // defer-max threshold (e^4: f16-acc safe)

typedef _Float16 h2 __attribute__((ext_vector_type(2)));
typedef _Float16 h8 __attribute__((ext_vector_type(8)));
typedef float    f32x4 __attribute__((ext_vector_type(4)));
typedef unsigned short us8 __attribute__((ext_vector_type(8)));

__device__ __forceinline__ unsigned short f2h(float f) {
    _Float16 h = (_Float16)f;
    return __builtin_bit_cast(unsigned short, h);
}
__device__ __forceinline__ float h2f(unsigned short u) {
    return (float)__builtin_bit_cast(_Float16, u);
}
__device__ __forceinline__ h2 shfl_h2(h2 v, int off) {
    int x = __builtin_bit_cast(int, v);
    return __builtin_bit_cast(h2, __shfl_xor(x, off));
}

__device__ __forceinline__ void edge_sd(const int* __restrict__ ei, int e, int& s, int& d) {
    if (e < NE0) { s = ei[e]; d = ei[NE0 + e]; }
    else { s = e - NE0; d = s; }
}

// ---------------- CSR build (by dst) ----------------
__global__ __launch_bounds__(256)
void hist_dst(const int* __restrict__ ei, int* __restrict__ deg) {
    int e = blockIdx.x * blockDim.x + threadIdx.x;
    if (e >= ETOT) return;
    int s, d; edge_sd(ei, e, s, d); (void)s;
    atomicAdd(&deg[d], 1);
}

__global__ __launch_bounds__(64)
void scan1(const int* __restrict__ deg, int* __restrict__ psum) {
    int i = blockIdx.x * 64 + threadIdx.x;
    int v = (i < NN) ? deg[i] : 0;
#pragma unroll
    for (int off = 1; off < 64; off <<= 1) {
        int t = __shfl_up(v, off);
        if ((int)threadIdx.x >= off) v += t;
    }
    if (threadIdx.x == 63) psum[blockIdx.x] = v;
}

__global__ __launch_bounds__(1024)
void scan2(int* __restrict__ psum) {
    __shared__ int sm[1024];
    int t = threadIdx.x;
    sm[t] = (t < SCAN_BLKS) ? psum[t] : 0;
    __syncthreads();
    for (int off = 1; off < 1024; off <<= 1) {
        int v = (t >= off) ? sm[t - off] : 0;
        __syncthreads();
        sm[t] += v;
        __syncthreads();
    }
    if (t < SCAN_BLKS) psum[t] = (t == 0) ? 0 : sm[t - 1];
}

__global__ __launch_bounds__(64)
void scan3(const int* __restrict__ deg, const int* __restrict__ psum,
           int* __restrict__ rowptr, int* __restrict__ cursor) {
    int i = blockIdx.x * 64 + threadIdx.x;
    int v = (i < NN) ? deg[i] : 0;
    int inc = v;
#pragma unroll
    for (int off = 1; off < 64; off <<= 1) {
        int t = __shfl_up(inc, off);
        if ((int)threadIdx.x >= off) inc += t;
    }
    int excl = inc - v + psum[blockIdx.x];
    if (i < NN) { rowptr[i] = excl; cursor[i] = excl; }
    if (i == NN - 1) rowptr[NN] = excl + v;   // == ETOT
}

__global__ __launch_bounds__(256)
void scatter_csr(const int* __restrict__ ei, int* __restrict__ cursor,
                 int* __restrict__ col) {
    int e = blockIdx.x * blockDim.x + threadIdx.x;
    if (e >= ETOT) return;
    int s, d; edge_sd(ei, e, s, d);
    int pos = atomicAdd(&cursor[d], 1);
    col[pos] = s;
}

// ---------------- weight pre-pack (all 4 matrices) + deg zero ----------------
__device__ __forceinline__ void wfrag_one(const float* W, unsigned short* Wf,
                                          int r, int KB, int NOUT) {
    int j = r & 7;
    int l = (r >> 3) & 63;
    int rest = r >> 9;
    int kb = rest % KB, t = rest / KB;
    int k = kb * 32 + (l >> 4) * 8 + j;
    int colj = t * 16 + (l & 15);
    Wf[r] = f2h(W[(size_t)k * NOUT + colj]);
}
__global__ __launch_bounds__(256)
void wfrag_all(const float* __restrict__ W2l, const float* __restrict__ W2r,
               const float* __restrict__ W3l, const float* __restrict__ W3r,
               unsigned short* __restrict__ Wf2l, unsigned short* __restrict__ Wf2r,
               unsigned short* __restrict__ Wf3l, unsigned short* __restrict__ Wf3r,
               int* __restrict__ deg) {
    int tid = blockIdx.x * 256 + threadIdx.x;   // [0, 4*32768)
    if (tid < NN) deg[tid] = 0;                 // fold memset
    int seg = tid >> 15;
    int r = tid & 32767;
    if (seg == 0)      wfrag_one(W2l, Wf2l, r, 8, 128);
    else if (seg == 1) wfrag_one(W2r, Wf2r, r, 8, 128);
    else if (seg == 2) wfrag_one(W3l, Wf3l, r, 4, 256);
    else               wfrag_one(W3r, Wf3r, r, 4, 256);
}

// ---------------- Q/R tables: Q = x@W1l + b1l, R = x@W1r + b1r (f16) ----------------
__global__ __launch_bounds__(256)
void qr_prep(const float* __restrict__ X,
             const float* __restrict__ W1l, const float* __restrict__ b1l,
             const float* __restrict__ W1r, const float* __restrict__ b1r,
             unsigned short* __restrict__ Q, unsigned short* __restrict__ R) {
    int j = blockIdx.x * 64 + (threadIdx.x & 63);
    int row0 = (blockIdx.y * 4 + (threadIdx.x >> 6)) * 8;
    float l0 = W1l[j], l1 = W1l[256 + j], l2 = W1l[512 + j], l3 = W1l[768 + j];
    float r0 = W1r[j], r1 = W1r[256 + j], r2 = W1r[512 + j], r3 = W1r[768 + j];
    float bl = b1l[j], br = b1r[j];
#pragma unroll
    for (int r = 0; r < 8; ++r) {
        int row = row0 + r;
        if (row >= NN) break;
        float4 xv = *reinterpret_cast<const float4*>(X + (size_t)row * 4);
        float q = fmaf(xv.x, l0, fmaf(xv.y, l1, fmaf(xv.z, l2, fmaf(xv.w, l3, bl))));
        float rr = fmaf(xv.x, r0, fmaf(xv.y, r1, fmaf(xv.z, r2, fmaf(xv.w, r3, br))));
        Q[(size_t)row * 256 + j] = f2h(q);
        R[(size_t)row * 256 + j] = f2h(rr);
    }
}

// ---------------- unified GATv2 aggregation ----------------
// SPLIT lane-groups (64/SPLIT lanes each) run independent online softmaxes over
// disjoint chunks of the node's edge list; merged at end via staged shfl_xor.
// CPL channels/lane (HC = CPL*64/SPLIT), REDW lanes per head group.
// 4-edge inner batches; branchy defer-max (THR=4); packed-f16 accumulation.
template<int CPL, int REDW, int SPLIT, bool RELU>
__global__ __launch_bounds__(256)
void gat_fused(const unsigned short* __restrict__ xl, const unsigned short* __restrict__ xr,
               const int* __restrict__ rowptr, const int* __restrict__ col,
               const float* __restrict__ att, const float* __restrict__ bias,
               unsigned short* __restrict__ out) {
    constexpr int GL = 64 / SPLIT;        // lanes per group
    constexpr int HC = CPL * GL;
    constexpr int NP = CPL / 2;
    int lane = threadIdx.x & 63;
    int grp = lane / GL;
    int gl = lane & (GL - 1);
    int node = (blockIdx.x * blockDim.x + threadIdx.x) >> 6;
    if (node >= NN) return;
    int ch0 = gl * CPL;

    const h2 c02 = (h2){(_Float16)0.2f, (_Float16)0.2f};
    h2 a2[NP];
#pragma unroll
    for (int p = 0; p < NP; ++p)
        a2[p] = (h2){(_Float16)att[ch0 + 2*p], (_Float16)att[ch0 + 2*p + 1]};
    h2 r2[NP];
    {
        const h2* rp = reinterpret_cast<const h2*>(xr + (size_t)node * HC + ch0);
#pragma unroll
        for (int p = 0; p < NP; ++p) r2[p] = rp[p];
    }

    float m = -INFINITY, l = 0.f;
    h2 acch[NP];
#pragma unroll
    for (int p = 0; p < NP; ++p) acch[p] = (h2){(_Float16)0.f, (_Float16)0.f};

    int beg = rowptr[node], end = rowptr[node + 1];
    int n = end - beg;
    int per = (n + SPLIT - 1) / SPLIT;
    int idx = beg + grp * per; if (idx > end) idx = end;
    int myEnd = idx + per; if (myEnd > end) myEnd = end;

    for (; idx + 3 < myEnd; idx += 4) {
        int s[4] = { col[idx], col[idx + 1], col[idx + 2], col[idx + 3] };
        h2 e[4][NP];
#pragma unroll
        for (int q = 0; q < 4; ++q) {
            const h2* pq = reinterpret_cast<const h2*>(xl + (size_t)s[q] * HC + ch0);
#pragma unroll
            for (int p = 0; p < NP; ++p) e[q][p] = pq[p];
        }
        float d[4] = { 0.f, 0.f, 0.f, 0.f };
#pragma unroll
        for (int p = 0; p < NP; ++p) {
#pragma unroll
            for (int q = 0; q < 4; ++q) {
                h2 u = e[q][p] + r2[p];
                u = __builtin_elementwise_max(u, u * c02);
                d[q] = __builtin_amdgcn_fdot2(u, a2[p], d[q], false);
            }
        }
#pragma unroll
        for (int off = REDW >> 1; off >= 1; off >>= 1) {
#pragma unroll
            for (int q = 0; q < 4; ++q) d[q] += __shfl_xor(d[q], off);
        }
        float pmax = fmaxf(fmaxf(d[0], d[1]), fmaxf(d[2], d[3]));
        if (pmax > m + DMAX_THR) {           // rare path (per head group)
            float sc = __expf(m - pmax);
            h2 sch = (h2){(_Float16)sc, (_Float16)sc};
            l *= sc;
#pragma unroll
            for (int p = 0; p < NP; ++p) acch[p] *= sch;
            m = pmax;
        }
        float pw[4];
#pragma unroll
        for (int q = 0; q < 4; ++q) pw[q] = __expf(d[q] - m);
        l += (pw[0] + pw[1]) + (pw[2] + pw[3]);
        h2 pg[4];
#pragma unroll
        for (int q = 0; q < 4; ++q)
            pg[q] = (h2){(_Float16)pw[q], (_Float16)pw[q]};
#pragma unroll
        for (int p = 0; p < NP; ++p) {
            h2 a = acch[p];
            a += pg[0] * e[0][p];
            a += pg[1] * e[1][p];
            a += pg[2] * e[2][p];
            a += pg[3] * e[3][p];
            acch[p] = a;
        }
    }
    for (; idx < myEnd; ++idx) {
        int s0 = col[idx];
        const h2* p0 = reinterpret_cast<const h2*>(xl + (size_t)s0 * HC + ch0);
        h2 e0[NP];
#pragma unroll
        for (int p = 0; p < NP; ++p) e0[p] = p0[p];
        float d0 = 0.f;
#pragma unroll
        for (int p = 0; p < NP; ++p) {
            h2 u0 = e0[p] + r2[p];
            u0 = __builtin_elementwise_max(u0, u0 * c02);
            d0 = __builtin_amdgcn_fdot2(u0, a2[p], d0, false);
        }
#pragma unroll
        for (int off = REDW >> 1; off >= 1; off >>= 1) d0 += __shfl_xor(d0, off);
        if (d0 > m + DMAX_THR) {
            float sc = __expf(m - d0);
            h2 sch = (h2){(_Float16)sc, (_Float16)sc};
            l *= sc;
#pragma unroll
            for (int p = 0; p < NP; ++p) acch[p] *= sch;
            m = d0;
        }
        float pw0 = __expf(d0 - m);
        l += pw0;
        h2 pg = (h2){(_Float16)pw0, (_Float16)pw0};
#pragma unroll
        for (int p = 0; p < NP; ++p)
            acch[p] += pg * e0[p];
    }

    // staged merges across groups (softmax-merge; -inf guarded for empty groups)
#pragma unroll
    for (int stage = GL; stage < 64; stage <<= 1) {
        float mo = __shfl_xor(m, stage);
        float lo = __shfl_xor(l, stage);
        float M = fmaxf(m, mo);
        float sA = (m > -INFINITY) ? __expf(m - M) : 0.f;
        float sB = (mo > -INFINITY) ? __expf(mo - M) : 0.f;
        l = l * sA + lo * sB;
        h2 sAh = (h2){(_Float16)sA, (_Float16)sA};
        h2 sBh = (h2){(_Float16)sB, (_Float16)sB};
#pragma unroll
        for (int p = 0; p < NP; ++p) {
            h2 ao = shfl_h2(acch[p], stage);
            acch[p] = acch[p] * sAh + ao * sBh;
        }
        m = M;
    }

    float inv = 1.f / (l + 1e-16f);
    unsigned short o[CPL];
#pragma unroll
    for (int p = 0; p < CPL; ++p) {
        float v = (float)acch[p >> 1][p & 1] * inv + bias[ch0 + p];
        if (RELU) v = fmaxf(v, 0.f);
        o[p] = f2h(v);
    }
    if (grp == 0) {
        if constexpr (CPL == 8) {
            us8 ov;
#pragma unroll
            for (int p = 0; p < 8; ++p) ov[p] = o[p];
            *reinterpret_cast<us8*>(out + (size_t)node * HC + ch0) = ov;
        } else {
            *reinterpret_cast<ushort4*>(out + (size_t)node * HC + ch0) =
                make_ushort4(o[0], o[1], o[2], o[3]);
        }
    }
}

// ---------------- fused MFMA GEMM (f16) ----------------
template<int KIN, int NOUT>
__global__ __launch_bounds__(256)
void gemm_mfma2(const unsigned short* __restrict__ X,
                const unsigned short* __restrict__ WfL, const float* __restrict__ bL,
                unsigned short* __restrict__ outL,
                const unsigned short* __restrict__ WfR, const float* __restrict__ bR,
                unsigned short* __restrict__ outR) {
    constexpr int KB = KIN / 32, NT = NOUT / 16;
    int lane = threadIdx.x & 63;
    int wv = threadIdx.x >> 6;
    int row0 = blockIdx.x * 64 + wv * 16;
    int r16 = lane & 15, kg = lane >> 4;

    int arow = row0 + r16; if (arow >= NN) arow = NN - 1;
    const unsigned short* xrow = X + (size_t)arow * KIN + kg * 8;
    h8 af[KB];
#pragma unroll
    for (int kb = 0; kb < KB; ++kb)
        af[kb] = *reinterpret_cast<const h8*>(xrow + kb * 32);

    const unsigned short* Wf[2] = { WfL, WfR };
    const float* bb[2] = { bL, bR };
    unsigned short* oo[2] = { outL, outR };

#pragma unroll
    for (int w = 0; w < 2; ++w) {
        const h8* wbase = reinterpret_cast<const h8*>(Wf[w]) + lane;
        const float* bw = bb[w];
        unsigned short* ow = oo[w];
#pragma unroll 1
        for (int t = 0; t < NT; ++t) {
            f32x4 acc = {0.f, 0.f, 0.f, 0.f};
            const h8* wp = wbase + (size_t)t * KB * 64;
#pragma unroll
            for (int kb = 0; kb < KB; ++kb)
                acc = __builtin_amdgcn_mfma_f32_16x16x32_f16(af[kb], wp[kb * 64], acc, 0, 0, 0);
            float bv = bw[t * 16 + r16];
#pragma unroll
            for (int rg = 0; rg < 4; ++rg) {
                int row = row0 + kg * 4 + rg;
                if (row < NN)
                    ow[(size_t)row * NOUT + t * 16 + r16] = f2h(acc[rg] + bv);
            }
        }
    }
}

// ---------------- pool + head MLP ----------------
__global__ __launch_bounds__(256)
void graph_bounds(const int* __restrict__ batch, float* __restrict__ cnt,
                  float* __restrict__ pooled) {
    int g = blockIdx.x, tid = threadIdx.x;
    pooled[g * 256 + tid] = 0.f;
    if (tid == 0) {
        int lo = 0, hi = NN;
        while (lo < hi) { int mid = (lo + hi) >> 1; if (batch[mid] < g) lo = mid + 1; else hi = mid; }
        int lo2 = lo, hi2 = NN;
        while (lo2 < hi2) { int mid = (lo2 + hi2) >> 1; if (batch[mid] < g + 1) lo2 = mid + 1; else hi2 = mid; }
        cnt[g] = (float)(lo2 - lo);
    }
}

__global__ __launch_bounds__(256)
void pool_sum(const unsigned short* __restrict__ h, const int* __restrict__ batch,
              float* pooled) {
    __shared__ int gb[32];
    int c = threadIdx.x;
    int n0 = blockIdx.x * 32;
    int n1 = min(n0 + 32, NN);
    int cnt = n1 - n0;
    if (c < cnt) gb[c] = batch[n0 + c];
    __syncthreads();
    if (gb[0] == gb[cnt - 1]) {
        float acc = 0.f;
#pragma unroll 4
        for (int i = 0; i < cnt; ++i) acc += h2f(h[(size_t)(n0 + i) * 256 + c]);
        atomicAdd(&pooled[gb[0] * 256 + c], acc);
    } else {
        int cur = gb[0]; float acc = 0.f;
        for (int i = 0; i < cnt; ++i) {
            int g = gb[i];
            if (g != cur) { atomicAdd(&pooled[cur * 256 + c], acc); acc = 0.f; cur = g; }
            acc += h2f(h[(size_t)(n0 + i) * 256 + c]);
        }
        atomicAdd(&pooled[cur * 256 + c], acc);
    }
}

__global__ __launch_bounds__(256)
void mlp_ln(const float* __restrict__ pooled, const float* __restrict__ cnt,
            const float* __restrict__ We1, const float* __restrict__ be1,
            const float* __restrict__ We2, const float* __restrict__ be2,
            const float* __restrict__ lng, const float* __restrict__ lnb,
            float* __restrict__ out) {
    __shared__ float p[256];
    __shared__ float t[512];
    __shared__ float red[8];
    int g = blockIdx.x, tid = threadIdx.x;
    p[tid] = pooled[g * 256 + tid] / fmaxf(cnt[g], 1.0f);
    __syncthreads();
    for (int jj = tid; jj < 512; jj += 256) {
        float s = be1[jj];
        for (int k = 0; k < 256; ++k) s = fmaf(p[k], We1[(size_t)k * 512 + jj], s);
        t[jj] = fmaxf(s, 0.f);
    }
    __syncthreads();
    float z = be2[tid];
    for (int k = 0; k < 512; ++k) z = fmaf(t[k], We2[(size_t)k * 256 + tid], z);
    float sv = z, sq = z * z;
#pragma unroll
    for (int off = 32; off >= 1; off >>= 1) {
        sv += __shfl_xor(sv, off);
        sq += __shfl_xor(sq, off);
    }
    int wv = tid >> 6;
    if ((tid & 63) == 0) { red[wv] = sv; red[4 + wv] = sq; }
    __syncthreads();
    float tot = red[0] + red[1] + red[2] + red[3];
    float totq = red[4] + red[5] + red[6] + red[7];
    float mu = tot * (1.f / 256.f);
    float var = totq * (1.f / 256.f) - mu * mu;
    float r = rsqrtf(var + 1e-5f);
    out[g * 256 + tid] = (z - mu) * r * lng[tid] + lnb[tid];
}

extern "C" void kernel_launch(void* const* d_in, const int* in_sizes, int n_in,
                              void* d_out, int out_size, void* d_ws, size_t ws_size,
                              hipStream_t stream) {
    const float* x   = (const float*)d_in[0];
    const int*   ei  = (const int*)d_in[1];
    const int*   bat = (const int*)d_in[2];
    const float *W1l = (const float*)d_in[3], *b1l = (const float*)d_in[4];
    const float *W1r = (const float*)d_in[5], *b1r = (const float*)d_in[6];
    const float *a1  = (const float*)d_in[7], *c1b = (const float*)d_in[8];
    const float *W2l = (const float*)d_in[9],  *b2l = (const float*)d_in[10];
    const float *W2r = (const float*)d_in[11], *b2r = (const float*)d_in[12];
    const float *a2  = (const float*)d_in[13], *c2b = (const float*)d_in[14];
    const float *W3l = (const float*)d_in[15], *b3l = (const float*)d_in[16];
    const float *W3r = (const float*)d_in[17], *b3r = (const float*)d_in[18];
    const float *a3  = (const float*)d_in[19], *c3b = (const float*)d_in[20];
    const float *We1 = (const float*)d_in[21], *be1 = (const float*)d_in[22];
    const float *We2 = (const float*)d_in[23], *be2 = (const float*)d_in[24];
    const float *lng = (const float*)d_in[25], *lnb = (const float*)d_in[26];

    char* base = (char*)d_ws;
    size_t off = 0;
    auto nxt = [&](size_t bytes) { char* p = base + off; off = (off + bytes + 255) & ~(size_t)255; return p; };
    unsigned short* Abuf = (unsigned short*)nxt((size_t)NN * 256 * 2);
    unsigned short* Bbuf = (unsigned short*)nxt((size_t)NN * 256 * 2);
    unsigned short* Hb16 = (unsigned short*)nxt((size_t)NN * 256 * 2);
    unsigned short* Qtab = (unsigned short*)nxt((size_t)NN * 256 * 2);
    unsigned short* Rtab = (unsigned short*)nxt((size_t)NN * 256 * 2);
    int* deg    = (int*)nxt(NN * 4);
    int* rowptr = (int*)nxt((NN + 1) * 4);
    int* cursor = (int*)nxt(NN * 4);
    int* colv   = (int*)nxt((size_t)ETOT * 4);
    int* psum   = (int*)nxt(1024 * 4);
    float* POOL = (float*)nxt(NG * 256 * 4);
    float* CNT  = (float*)nxt(NG * 4);
    unsigned short* Wf2l = (unsigned short*)nxt(256 * 128 * 2);
    unsigned short* Wf2r = (unsigned short*)nxt(256 * 128 * 2);
    unsigned short* Wf3l = (unsigned short*)nxt(128 * 256 * 2);
    unsigned short* Wf3r = (unsigned short*)nxt(128 * 256 * 2);

    const int GEMM_BLKS = (NN + 63) / 64;
    const int NB_NODE = (NN + 3) / 4;   // wave-per-node, 4 waves/block

    // ---- weight pre-pack (also zeroes deg) ----
    wfrag_all<<<(4 * 32768) / 256, 256, 0, stream>>>(W2l, W2r, W3l, W3r,
                                                     Wf2l, Wf2r, Wf3l, Wf3r, deg);
    // ---- CSR build ----
    hist_dst<<<(ETOT + 255) / 256, 256, 0, stream>>>(ei, deg);
    scan1<<<SCAN_BLKS, 64, 0, stream>>>(deg, psum);
    scan2<<<1, 1024, 0, stream>>>(psum);
    scan3<<<SCAN_BLKS, 64, 0, stream>>>(deg, psum, rowptr, cursor);
    scatter_csr<<<(ETOT + 255) / 256, 256, 0, stream>>>(ei, cursor, colv);

    // ---- Q/R tables ----
    {
        dim3 g(4, (NN + 31) / 32);
        qr_prep<<<g, 256, 0, stream>>>(x, W1l, b1l, W1r, b1r, Qtab, Rtab);
    }

    // ---- Layer 1 (H=4,C=64): half-split, CPL=8, head=8 lanes ----
    gat_fused<8, 8, 2, true><<<NB_NODE, 256, 0, stream>>>(Qtab, Rtab, rowptr, colv, a1, c1b, Hb16);

    // ---- Layer 2: 256 -> (H=2,C=64): quarter-split, CPL=8, head=8 lanes ----
    gemm_mfma2<256, 128><<<GEMM_BLKS, 256, 0, stream>>>(Hb16, Wf2l, b2l, Abuf, Wf2r, b2r, Bbuf);
    gat_fused<8, 8, 4, true><<<NB_NODE, 256, 0, stream>>>(Abuf, Bbuf, rowptr, colv, a2, c2b, Hb16);

    // ---- Layer 3: 128 -> (H=1,C=256): half-split, CPL=8, head=32 lanes ----
    gemm_mfma2<128, 256><<<GEMM_BLKS, 256, 0, stream>>>(Hb16, Wf3l, b3l, Abuf, Wf3r, b3r, Bbuf);
    gat_fused<8, 32, 2, false><<<NB_NODE, 256, 0, stream>>>(Abuf, Bbuf, rowptr, colv, a3, c3b, Hb16);

    // ---- pool + MLP + LN ----
    graph_bounds<<<NG, 256, 0, stream>>>(bat, CNT, POOL);
    pool_sum<<<(NN + 31) / 32, 256, 0, stream>>>(Hb16, bat, POOL);
    mlp_ln<<<NG, 256, 0, stream>>>(POOL, CNT, We1, be1, We2, be2, lng, lnb, (float*)d_out);
}